// Round 2
// baseline (2583.027 us; speedup 1.0000x reference)
//
#include <hip/hip_runtime.h>
#include <hip/hip_bf16.h>

#define N_WORD  30000
#define N_TOPIC 512
#define N_DOC   10000
#define E_WT    262144
#define E_WD    262144
#define E_TD    131072
#define DIM     256

typedef __attribute__((ext_vector_type(8))) short bf16x8;
typedef __attribute__((ext_vector_type(4))) float f32x4;
typedef __attribute__((ext_vector_type(4))) short short4v;

__device__ __forceinline__ float bf2f(unsigned short u) {
    unsigned int v = ((unsigned int)u) << 16;
    float f;
    __builtin_memcpy(&f, &v, 4);
    return f;
}

__device__ __forceinline__ short f2bf(float f) {
    __hip_bfloat16 h = __float2bfloat16(f);   // RNE
    short s;
    __builtin_memcpy(&s, &h, 2);
    return s;
}

// C[M,256] = A[M,256] @ W[256,256]^T + bias. A,W,bias f32; C bf16 (workspace).
// f32 loaded, converted to bf16 fragments, f32 MFMA accumulate.
// One wave computes a 16-row x 256-col strip.
__global__ __launch_bounds__(256) void gemm_nt_bias(
    const float* __restrict__ A,
    const float* __restrict__ W,
    const float* __restrict__ bias,
    __hip_bfloat16* __restrict__ C,
    int M)
{
    const int wave = threadIdx.x >> 6;
    const int lane = threadIdx.x & 63;
    const int m0 = blockIdx.x * 64 + wave * 16;
    if (m0 >= M) return;                 // whole-wave exit; no barriers in kernel
    const int lr = lane & 15;            // A-row / B-col within 16x16 tile
    const int kh = lane >> 4;            // k-quarter group (0..3)

    int ar = m0 + lr; if (ar > M - 1) ar = M - 1;   // clamp (dup loads OK, stores guarded)
    bf16x8 afrag[8];
    #pragma unroll
    for (int kk = 0; kk < 8; ++kk) {
        const float* ap = A + (size_t)ar * DIM + kk * 32 + kh * 8;
        f32x4 a0 = *reinterpret_cast<const f32x4*>(ap);
        f32x4 a1 = *reinterpret_cast<const f32x4*>(ap + 4);
        bf16x8 fr;
        fr[0] = f2bf(a0[0]); fr[1] = f2bf(a0[1]); fr[2] = f2bf(a0[2]); fr[3] = f2bf(a0[3]);
        fr[4] = f2bf(a1[0]); fr[5] = f2bf(a1[1]); fr[6] = f2bf(a1[2]); fr[7] = f2bf(a1[3]);
        afrag[kk] = fr;
    }

    #pragma unroll
    for (int ct = 0; ct < 16; ++ct) {
        f32x4 acc = {0.f, 0.f, 0.f, 0.f};
        #pragma unroll
        for (int kk = 0; kk < 8; ++kk) {
            const float* wp = W + (size_t)(ct * 16 + lr) * DIM + kk * 32 + kh * 8;
            f32x4 b0 = *reinterpret_cast<const f32x4*>(wp);
            f32x4 b1 = *reinterpret_cast<const f32x4*>(wp + 4);
            bf16x8 bfrag;
            bfrag[0] = f2bf(b0[0]); bfrag[1] = f2bf(b0[1]); bfrag[2] = f2bf(b0[2]); bfrag[3] = f2bf(b0[3]);
            bfrag[4] = f2bf(b1[0]); bfrag[5] = f2bf(b1[1]); bfrag[6] = f2bf(b1[2]); bfrag[7] = f2bf(b1[3]);
            acc = __builtin_amdgcn_mfma_f32_16x16x32_bf16(afrag[kk], bfrag, acc, 0, 0, 0);
        }
        float bb = bias[ct * 16 + lr];
        #pragma unroll
        for (int j = 0; j < 4; ++j) {
            int row = m0 + kh * 4 + j;   // D: col = lane&15, row = (lane>>4)*4 + j
            if (row < M)
                C[(size_t)row * DIM + ct * 16 + lr] = __float2bfloat16(acc[j] + bb);
        }
    }
}

// One wave per edge: gather 256-dim bf16 row of Wh[src], scale by f32 edge weight,
// f32-atomicAdd into acc[dst], count degree.
__global__ __launch_bounds__(256) void edge_scatter(
    const __hip_bfloat16* __restrict__ Wh,
    const float* __restrict__ ew,
    const int* __restrict__ src,
    const int* __restrict__ dst,
    float* __restrict__ acc,
    float* __restrict__ deg,
    int E)
{
    const int lane = threadIdx.x & 63;
    const int wid = (int)((blockIdx.x * (size_t)blockDim.x + threadIdx.x) >> 6);
    const int nw  = (int)(((size_t)gridDim.x * blockDim.x) >> 6);
    const unsigned short* Whu = (const unsigned short*)Wh;

    for (int e = wid; e < E; e += nw) {
        const int s = src[e];
        const int d = dst[e];
        const float we = ew[e];
        short4v v = *reinterpret_cast<const short4v*>(Whu + (size_t)s * DIM + lane * 4);
        float* q = acc + (size_t)d * DIM + lane * 4;
        atomicAdd(q + 0, bf2f((unsigned short)v.x) * we);
        atomicAdd(q + 1, bf2f((unsigned short)v.y) * we);
        atomicAdd(q + 2, bf2f((unsigned short)v.z) * we);
        atomicAdd(q + 3, bf2f((unsigned short)v.w) * we);
        if (lane == 0) atomicAdd(deg + d, 1.0f);
    }
}

__global__ __launch_bounds__(256) void topic_final(
    const float* __restrict__ acc, const float* __restrict__ deg,
    float* __restrict__ out)
{
    int i = blockIdx.x * 256 + threadIdx.x;
    if (i >= N_TOPIC * DIM) return;
    float dv = deg[i >> 8];
    dv = dv > 1.f ? dv : 1.f;
    out[i] = acc[i] / dv;
}

__global__ __launch_bounds__(256) void doc_final(
    const float* __restrict__ awd, const float* __restrict__ dwd,
    const float* __restrict__ atd, const float* __restrict__ dtd,
    float* __restrict__ out)
{
    int i = blockIdx.x * 256 + threadIdx.x;
    if (i >= N_DOC * DIM) return;
    int node = i >> 8;
    float m1 = awd[i] / fmaxf(dwd[node], 1.f);
    float m2 = atd[i] / fmaxf(dtd[node], 1.f);
    float h = m1 + m2;
    out[i] = h > 0.f ? h : 0.f;
}

extern "C" void kernel_launch(void* const* d_in, const int* in_sizes, int n_in,
                              void* d_out, int out_size, void* d_ws, size_t ws_size,
                              hipStream_t stream)
{
    const float* feat_word  = (const float*)d_in[0];
    const float* feat_topic = (const float*)d_in[1];
    /* feat_doc (d_in[2]) unused by the reference output */
    const int* wt_src = (const int*)d_in[3];
    const int* wt_dst = (const int*)d_in[4];
    const int* wd_src = (const int*)d_in[5];
    const int* wd_dst = (const int*)d_in[6];
    const int* td_src = (const int*)d_in[7];
    const int* td_dst = (const int*)d_in[8];
    const float* w_wt = (const float*)d_in[9];
    const float* w_wd = (const float*)d_in[10];
    const float* w_td = (const float*)d_in[11];
    const float* Wt   = (const float*)d_in[12];
    const float* bt   = (const float*)d_in[13];
    const float* Wd   = (const float*)d_in[14];
    const float* bd   = (const float*)d_in[15];
    const float* Wtd  = (const float*)d_in[16];
    const float* btd  = (const float*)d_in[17];

    char* ws = (char*)d_ws;
    // Workspace layout (bytes), total ~52.1 MB:
    __hip_bfloat16* Wh_wt = (__hip_bfloat16*)(ws + 0);          // 30000*256*2 = 15,360,000
    __hip_bfloat16* Wh_wd = (__hip_bfloat16*)(ws + 15360000);   // 15,360,000
    __hip_bfloat16* Wh_td = (__hip_bfloat16*)(ws + 30720000);   // 512*256*2 = 262,144
    float* acc_topic = (float*)(ws + 30982144);                 // 512*256*4  = 524,288
    float* acc_wd    = (float*)(ws + 31506432);                 // 10000*256*4 = 10,240,000
    float* acc_td    = (float*)(ws + 41746432);                 // 10,240,000
    float* deg_topic = (float*)(ws + 51986432);                 // 2,048
    float* deg_wd    = (float*)(ws + 51988480);                 // 40,000
    float* deg_td    = (float*)(ws + 52028480);                 // 40,000  -> end 52,068,480

    // zero all accumulators + degrees (one contiguous region), every call
    hipMemsetAsync(ws + 30982144, 0, 52068480 - 30982144, stream);

    // per-relation linears (f32 in -> bf16 Wh out)
    gemm_nt_bias<<<(N_WORD + 63) / 64, 256, 0, stream>>>(feat_word, Wt, bt, Wh_wt, N_WORD);
    gemm_nt_bias<<<(N_WORD + 63) / 64, 256, 0, stream>>>(feat_word, Wd, bd, Wh_wd, N_WORD);
    gemm_nt_bias<<<(N_TOPIC + 63) / 64, 256, 0, stream>>>(feat_topic, Wtd, btd, Wh_td, N_TOPIC);

    // u_mul_e + scatter-sum (+degree)
    edge_scatter<<<4096, 256, 0, stream>>>(Wh_wt, w_wt, wt_src, wt_dst, acc_topic, deg_topic, E_WT);
    edge_scatter<<<4096, 256, 0, stream>>>(Wh_wd, w_wd, wd_src, wd_dst, acc_wd, deg_wd, E_WD);
    edge_scatter<<<2048, 256, 0, stream>>>(Wh_td, w_td, td_src, td_dst, acc_td, deg_td, E_TD);

    // outputs (f32): [feat_word 30000x256 | h_topic 512x256 | h_doc 10000x256]
    float* out = (float*)d_out;
    hipMemcpyAsync(out, feat_word, (size_t)N_WORD * DIM * sizeof(float),
                   hipMemcpyDeviceToDevice, stream);
    topic_final<<<(N_TOPIC * DIM) / 256, 256, 0, stream>>>(
        acc_topic, deg_topic, out + (size_t)N_WORD * DIM);
    doc_final<<<(N_DOC * DIM) / 256, 256, 0, stream>>>(
        acc_wd, deg_wd, acc_td, deg_td, out + (size_t)(N_WORD + N_TOPIC) * DIM);
}

// Round 3
// 578.952 us; speedup vs baseline: 4.4616x; 4.4616x over previous
//
#include <hip/hip_runtime.h>
#include <hip/hip_bf16.h>

#define N_WORD  30000
#define N_TOPIC 512
#define N_DOC   10000
#define E_WT    262144
#define E_WD    262144
#define E_TD    131072
#define DIM     256
#define TOPIC_C 8   // chunk-waves per topic node

typedef __attribute__((ext_vector_type(8))) short bf16x8;
typedef __attribute__((ext_vector_type(4))) float f32x4;
typedef __attribute__((ext_vector_type(4))) short short4v;

__device__ __forceinline__ float bf2f(unsigned short u) {
    unsigned int v = ((unsigned int)u) << 16;
    float f;
    __builtin_memcpy(&f, &v, 4);
    return f;
}
__device__ __forceinline__ short f2bf(float f) {
    __hip_bfloat16 h = __float2bfloat16(f);   // RNE
    short s;
    __builtin_memcpy(&s, &h, 2);
    return s;
}

// ---- convert the three f32 weight matrices to bf16 (once per call) ----
__global__ __launch_bounds__(256) void cvt_w3(
    const float* __restrict__ a, const float* __restrict__ b, const float* __restrict__ c,
    __hip_bfloat16* __restrict__ oa, __hip_bfloat16* __restrict__ ob, __hip_bfloat16* __restrict__ oc)
{
    int i = blockIdx.x * 256 + threadIdx.x;       // 65536 threads, 1 elem each x3
    if (i >= DIM * DIM) return;
    oa[i] = __float2bfloat16(a[i]);
    ob[i] = __float2bfloat16(b[i]);
    oc[i] = __float2bfloat16(c[i]);
}

// C[M,256] = A[M,256](f32) @ Wbf[256,256]^T(bf16) + bias(f32) -> bf16 C.
// One wave computes a 16-row x 256-col strip via mfma_f32_16x16x32_bf16.
__global__ __launch_bounds__(256) void gemm_nt_bias(
    const float* __restrict__ A,
    const __hip_bfloat16* __restrict__ Wbf,
    const float* __restrict__ bias,
    __hip_bfloat16* __restrict__ C,
    int M)
{
    const int wave = threadIdx.x >> 6;
    const int lane = threadIdx.x & 63;
    const int m0 = blockIdx.x * 64 + wave * 16;
    if (m0 >= M) return;                 // whole-wave exit; no barriers in kernel
    const int lr = lane & 15;
    const int kh = lane >> 4;

    int ar = m0 + lr; if (ar > M - 1) ar = M - 1;   // clamp (dup loads OK, stores guarded)
    bf16x8 afrag[8];
    #pragma unroll
    for (int kk = 0; kk < 8; ++kk) {
        const float* ap = A + (size_t)ar * DIM + kk * 32 + kh * 8;
        f32x4 a0 = *reinterpret_cast<const f32x4*>(ap);
        f32x4 a1 = *reinterpret_cast<const f32x4*>(ap + 4);
        bf16x8 fr;
        fr[0] = f2bf(a0[0]); fr[1] = f2bf(a0[1]); fr[2] = f2bf(a0[2]); fr[3] = f2bf(a0[3]);
        fr[4] = f2bf(a1[0]); fr[5] = f2bf(a1[1]); fr[6] = f2bf(a1[2]); fr[7] = f2bf(a1[3]);
        afrag[kk] = fr;
    }
    const unsigned short* Wu = (const unsigned short*)Wbf;

    #pragma unroll
    for (int ct = 0; ct < 16; ++ct) {
        f32x4 acc = {0.f, 0.f, 0.f, 0.f};
        #pragma unroll
        for (int kk = 0; kk < 8; ++kk) {
            bf16x8 bfrag = *reinterpret_cast<const bf16x8*>(
                Wu + (size_t)(ct * 16 + lr) * DIM + kk * 32 + kh * 8);
            acc = __builtin_amdgcn_mfma_f32_16x16x32_bf16(afrag[kk], bfrag, acc, 0, 0, 0);
        }
        float bb = bias[ct * 16 + lr];
        #pragma unroll
        for (int j = 0; j < 4; ++j) {
            int row = m0 + kh * 4 + j;   // D: col = lane&15, row = (lane>>4)*4 + j
            if (row < M)
                C[(size_t)row * DIM + ct * 16 + lr] = __float2bfloat16(acc[j] + bb);
        }
    }
}

// ---- CSR build ----
__global__ __launch_bounds__(256) void hist_kernel(
    const int* __restrict__ dst, int E, int* __restrict__ cnt)
{
    int i = blockIdx.x * 256 + threadIdx.x;
    int n = gridDim.x * 256;
    for (int e = i; e < E; e += n) atomicAdd(&cnt[dst[e]], 1);
}

// single-block exclusive scan; writes row starts and a working cursor copy
__global__ __launch_bounds__(256) void exscan_kernel(
    const int* __restrict__ cnt, int* __restrict__ row, int* __restrict__ cur, int n)
{
    __shared__ int buf[256];
    __shared__ int carry;
    if (threadIdx.x == 0) carry = 0;
    __syncthreads();
    for (int base = 0; base < n; base += 256) {
        int i = base + (int)threadIdx.x;
        int v = (i < n) ? cnt[i] : 0;
        buf[threadIdx.x] = v;
        __syncthreads();
        #pragma unroll
        for (int off = 1; off < 256; off <<= 1) {
            int t = (threadIdx.x >= (unsigned)off) ? buf[threadIdx.x - off] : 0;
            __syncthreads();
            buf[threadIdx.x] += t;
            __syncthreads();
        }
        int excl = carry + buf[threadIdx.x] - v;
        if (i < n) { row[i] = excl; cur[i] = excl; }
        __syncthreads();
        if (threadIdx.x == 255) carry += buf[255];
        __syncthreads();
    }
}

__global__ __launch_bounds__(256) void scatter_kernel(
    const int* __restrict__ dst, int E, int* __restrict__ cur, int* __restrict__ csr)
{
    int i = blockIdx.x * 256 + threadIdx.x;
    int n = gridDim.x * 256;
    for (int e = i; e < E; e += n) {
        int pos = atomicAdd(&cur[dst[e]], 1);
        csr[pos] = e;
    }
}

// ---- topic gather: 8 chunk-waves per node, plain partial stores (no atomics) ----
__global__ __launch_bounds__(256) void gather_topic(
    const __hip_bfloat16* __restrict__ Wh, const float* __restrict__ ew,
    const int* __restrict__ src, const int* __restrict__ csr,
    const int* __restrict__ row, const int* __restrict__ cnt,
    float* __restrict__ part)
{
    int wid = (blockIdx.x * 256 + (int)threadIdx.x) >> 6;
    int lane = threadIdx.x & 63;
    int node = wid >> 3;
    int chunk = wid & (TOPIC_C - 1);
    if (node >= N_TOPIC) return;
    int start = row[node], deg = cnt[node];
    const unsigned short* Whu = (const unsigned short*)Wh;
    float a0 = 0.f, a1 = 0.f, a2 = 0.f, a3 = 0.f;
    for (int j = chunk; j < deg; j += TOPIC_C) {
        int e = csr[start + j];
        int s = src[e];
        float w = ew[e];
        short4v v = *reinterpret_cast<const short4v*>(Whu + (size_t)s * DIM + lane * 4);
        a0 += bf2f((unsigned short)v.x) * w;
        a1 += bf2f((unsigned short)v.y) * w;
        a2 += bf2f((unsigned short)v.z) * w;
        a3 += bf2f((unsigned short)v.w) * w;
    }
    f32x4 r = {a0, a1, a2, a3};
    *reinterpret_cast<f32x4*>(part + ((size_t)chunk * N_TOPIC + node) * DIM + lane * 4) = r;
}

__global__ __launch_bounds__(256) void topic_final(
    const float* __restrict__ part, const int* __restrict__ cnt,
    float* __restrict__ out)
{
    int i = blockIdx.x * 256 + threadIdx.x;
    if (i >= N_TOPIC * DIM) return;
    float s = 0.f;
    #pragma unroll
    for (int c = 0; c < TOPIC_C; ++c) s += part[(size_t)c * N_TOPIC * DIM + i];
    int d = cnt[i >> 8];
    out[i] = s / (float)(d > 1 ? d : 1);
}

// ---- doc gather: one wave per doc node, both relations fused, direct out store ----
__global__ __launch_bounds__(256) void gather_doc(
    const __hip_bfloat16* __restrict__ Wh_wd, const float* __restrict__ w_wd,
    const int* __restrict__ wd_src, const int* __restrict__ csr_wd,
    const int* __restrict__ row_wd, const int* __restrict__ cnt_wd,
    const __hip_bfloat16* __restrict__ Wh_td, const float* __restrict__ w_td,
    const int* __restrict__ td_src, const int* __restrict__ csr_td,
    const int* __restrict__ row_td, const int* __restrict__ cnt_td,
    float* __restrict__ out)
{
    int node = (blockIdx.x * 256 + (int)threadIdx.x) >> 6;
    int lane = threadIdx.x & 63;
    if (node >= N_DOC) return;

    const unsigned short* WuA = (const unsigned short*)Wh_wd;
    const unsigned short* WuB = (const unsigned short*)Wh_td;

    float a0 = 0.f, a1 = 0.f, a2 = 0.f, a3 = 0.f;
    {
        int start = row_wd[node], deg = cnt_wd[node];
        for (int j = 0; j < deg; ++j) {
            int e = csr_wd[start + j];
            int s = wd_src[e];
            float w = w_wd[e];
            short4v v = *reinterpret_cast<const short4v*>(WuA + (size_t)s * DIM + lane * 4);
            a0 += bf2f((unsigned short)v.x) * w;
            a1 += bf2f((unsigned short)v.y) * w;
            a2 += bf2f((unsigned short)v.z) * w;
            a3 += bf2f((unsigned short)v.w) * w;
        }
        float inv = 1.f / (float)(deg > 1 ? deg : 1);
        a0 *= inv; a1 *= inv; a2 *= inv; a3 *= inv;
    }
    float b0 = 0.f, b1 = 0.f, b2 = 0.f, b3 = 0.f;
    {
        int start = row_td[node], deg = cnt_td[node];
        for (int j = 0; j < deg; ++j) {
            int e = csr_td[start + j];
            int s = td_src[e];
            float w = w_td[e];
            short4v v = *reinterpret_cast<const short4v*>(WuB + (size_t)s * DIM + lane * 4);
            b0 += bf2f((unsigned short)v.x) * w;
            b1 += bf2f((unsigned short)v.y) * w;
            b2 += bf2f((unsigned short)v.z) * w;
            b3 += bf2f((unsigned short)v.w) * w;
        }
        float inv = 1.f / (float)(deg > 1 ? deg : 1);
        b0 *= inv; b1 *= inv; b2 *= inv; b3 *= inv;
    }
    f32x4 r;
    r[0] = fmaxf(a0 + b0, 0.f);
    r[1] = fmaxf(a1 + b1, 0.f);
    r[2] = fmaxf(a2 + b2, 0.f);
    r[3] = fmaxf(a3 + b3, 0.f);
    *reinterpret_cast<f32x4*>(out + (size_t)node * DIM + lane * 4) = r;
}

extern "C" void kernel_launch(void* const* d_in, const int* in_sizes, int n_in,
                              void* d_out, int out_size, void* d_ws, size_t ws_size,
                              hipStream_t stream)
{
    const float* feat_word  = (const float*)d_in[0];
    const float* feat_topic = (const float*)d_in[1];
    /* feat_doc (d_in[2]) unused by the reference output */
    const int* wt_src = (const int*)d_in[3];
    const int* wt_dst = (const int*)d_in[4];
    const int* wd_src = (const int*)d_in[5];
    const int* wd_dst = (const int*)d_in[6];
    const int* td_src = (const int*)d_in[7];
    const int* td_dst = (const int*)d_in[8];
    const float* w_wt = (const float*)d_in[9];
    const float* w_wd = (const float*)d_in[10];
    const float* w_td = (const float*)d_in[11];
    const float* Wt   = (const float*)d_in[12];
    const float* bt   = (const float*)d_in[13];
    const float* Wd   = (const float*)d_in[14];
    const float* bd   = (const float*)d_in[15];
    const float* Wtd  = (const float*)d_in[16];
    const float* btd  = (const float*)d_in[17];

    char* ws = (char*)d_ws;
    // Workspace layout (bytes), ~38.4 MB total:
    __hip_bfloat16* Wh_wt = (__hip_bfloat16*)(ws + 0);          // 15,360,000
    __hip_bfloat16* Wh_wd = (__hip_bfloat16*)(ws + 15360000);   // 15,360,000
    __hip_bfloat16* Wh_td = (__hip_bfloat16*)(ws + 30720000);   // 262,144
    __hip_bfloat16* Wbf_t  = (__hip_bfloat16*)(ws + 30982144);  // 131,072
    __hip_bfloat16* Wbf_d  = (__hip_bfloat16*)(ws + 31113216);  // 131,072
    __hip_bfloat16* Wbf_td = (__hip_bfloat16*)(ws + 31244288);  // 131,072
    float* part_topic = (float*)(ws + 31375360);                // 8*512*256*4 = 4,194,304
    int* cnt_wt = (int*)(ws + 35569664);                        // 2,048   } zero region
    int* cnt_wd = (int*)(ws + 35571712);                        // 40,000  }
    int* cnt_td = (int*)(ws + 35611712);                        // 40,000  } -> 35,651,712
    int* row_wt = (int*)(ws + 35651712);                        // 2,048
    int* row_wd = (int*)(ws + 35653760);                        // 40,000
    int* row_td = (int*)(ws + 35693760);                        // 40,000
    int* cur_wt = (int*)(ws + 35733760);                        // 2,048
    int* cur_wd = (int*)(ws + 35735808);                        // 40,000
    int* cur_td = (int*)(ws + 35775808);                        // 40,000
    int* csr_wt = (int*)(ws + 35815808);                        // 1,048,576
    int* csr_wd = (int*)(ws + 36864384);                        // 1,048,576
    int* csr_td = (int*)(ws + 37912960);                        // 524,288 -> 38,437,248

    // zero the histogram counters only
    hipMemsetAsync(ws + 35569664, 0, 82048, stream);

    // weights -> bf16 once
    cvt_w3<<<(DIM * DIM + 255) / 256, 256, 0, stream>>>(Wt, Wd, Wtd, Wbf_t, Wbf_d, Wbf_td);

    // per-relation linears (f32 A x bf16 W -> bf16 Wh)
    gemm_nt_bias<<<(N_WORD + 63) / 64, 256, 0, stream>>>(feat_word, Wbf_t, bt, Wh_wt, N_WORD);
    gemm_nt_bias<<<(N_WORD + 63) / 64, 256, 0, stream>>>(feat_word, Wbf_d, bd, Wh_wd, N_WORD);
    gemm_nt_bias<<<(N_TOPIC + 63) / 64, 256, 0, stream>>>(feat_topic, Wbf_td, btd, Wh_td, N_TOPIC);

    // CSR build (histogram -> exclusive scan -> cursor scatter)
    hist_kernel<<<256, 256, 0, stream>>>(wt_dst, E_WT, cnt_wt);
    hist_kernel<<<256, 256, 0, stream>>>(wd_dst, E_WD, cnt_wd);
    hist_kernel<<<128, 256, 0, stream>>>(td_dst, E_TD, cnt_td);
    exscan_kernel<<<1, 256, 0, stream>>>(cnt_wt, row_wt, cur_wt, N_TOPIC);
    exscan_kernel<<<1, 256, 0, stream>>>(cnt_wd, row_wd, cur_wd, N_DOC);
    exscan_kernel<<<1, 256, 0, stream>>>(cnt_td, row_td, cur_td, N_DOC);
    scatter_kernel<<<256, 256, 0, stream>>>(wt_dst, E_WT, cur_wt, csr_wt);
    scatter_kernel<<<256, 256, 0, stream>>>(wd_dst, E_WD, cur_wd, csr_wd);
    scatter_kernel<<<128, 256, 0, stream>>>(td_dst, E_TD, cur_td, csr_td);

    float* out = (float*)d_out;
    // word output = input features (d2d copy)
    hipMemcpyAsync(out, feat_word, (size_t)N_WORD * DIM * sizeof(float),
                   hipMemcpyDeviceToDevice, stream);

    // gathers (no f32 atomics anywhere)
    gather_topic<<<(N_TOPIC * TOPIC_C) / 4, 256, 0, stream>>>(
        Wh_wt, w_wt, wt_src, csr_wt, row_wt, cnt_wt, part_topic);
    topic_final<<<(N_TOPIC * DIM) / 256, 256, 0, stream>>>(
        part_topic, cnt_wt, out + (size_t)N_WORD * DIM);
    gather_doc<<<(N_DOC + 3) / 4, 256, 0, stream>>>(
        Wh_wd, w_wd, wd_src, csr_wd, row_wd, cnt_wd,
        Wh_td, w_td, td_src, csr_td, row_td, cnt_td,
        out + (size_t)(N_WORD + N_TOPIC) * DIM);
}

// Round 4
// 474.304 us; speedup vs baseline: 5.4459x; 1.2206x over previous
//
#include <hip/hip_runtime.h>
#include <hip/hip_bf16.h>

#define N_WORD  30000
#define N_TOPIC 512
#define N_DOC   10000
#define E_WT    262144
#define E_WD    262144
#define E_TD    131072
#define DIM     256
#define TOPIC_C 16   // chunk-waves per topic node

typedef __attribute__((ext_vector_type(8))) short bf16x8;
typedef __attribute__((ext_vector_type(4))) float f32x4;
typedef __attribute__((ext_vector_type(4))) short short4v;

__device__ __forceinline__ float bf2f(unsigned short u) {
    unsigned int v = ((unsigned int)u) << 16;
    float f;
    __builtin_memcpy(&f, &v, 4);
    return f;
}
__device__ __forceinline__ short f2bf(float f) {
    __hip_bfloat16 h = __float2bfloat16(f);   // RNE
    short s;
    __builtin_memcpy(&s, &h, 2);
    return s;
}
__device__ __forceinline__ void acc4(float& a0, float& a1, float& a2, float& a3,
                                     short4v v, float w) {
    a0 += bf2f((unsigned short)v.x) * w;
    a1 += bf2f((unsigned short)v.y) * w;
    a2 += bf2f((unsigned short)v.z) * w;
    a3 += bf2f((unsigned short)v.w) * w;
}

// ---- f32 -> bf16 cast, 8 elems/thread ----
__global__ __launch_bounds__(256) void cvt_f32_bf16(
    const float* __restrict__ in, __hip_bfloat16* __restrict__ out, int n8)
{
    int i = blockIdx.x * 256 + threadIdx.x;
    if (i >= n8) return;
    f32x4 a = *reinterpret_cast<const f32x4*>(in + (size_t)i * 8);
    f32x4 b = *reinterpret_cast<const f32x4*>(in + (size_t)i * 8 + 4);
    bf16x8 r;
    r[0] = f2bf(a[0]); r[1] = f2bf(a[1]); r[2] = f2bf(a[2]); r[3] = f2bf(a[3]);
    r[4] = f2bf(b[0]); r[5] = f2bf(b[1]); r[6] = f2bf(b[2]); r[7] = f2bf(b[3]);
    *reinterpret_cast<bf16x8*>((unsigned short*)out + (size_t)i * 8) = r;
}

// ---- convert the three f32 weight matrices to bf16 ----
__global__ __launch_bounds__(256) void cvt_w3(
    const float* __restrict__ a, const float* __restrict__ b, const float* __restrict__ c,
    __hip_bfloat16* __restrict__ oa, __hip_bfloat16* __restrict__ ob, __hip_bfloat16* __restrict__ oc)
{
    int i = blockIdx.x * 256 + threadIdx.x;
    if (i >= DIM * DIM) return;
    oa[i] = __float2bfloat16(a[i]);
    ob[i] = __float2bfloat16(b[i]);
    oc[i] = __float2bfloat16(c[i]);
}

// ---- CSR build ----
__global__ __launch_bounds__(256) void hist_kernel(
    const int* __restrict__ dst, int E, int* __restrict__ cnt)
{
    int i = blockIdx.x * 256 + threadIdx.x;
    int n = gridDim.x * 256;
    for (int e = i; e < E; e += n) atomicAdd(&cnt[dst[e]], 1);
}

__global__ __launch_bounds__(256) void exscan_kernel(
    const int* __restrict__ cnt, int* __restrict__ row, int* __restrict__ cur, int n)
{
    __shared__ int buf[256];
    __shared__ int carry;
    if (threadIdx.x == 0) carry = 0;
    __syncthreads();
    for (int base = 0; base < n; base += 256) {
        int i = base + (int)threadIdx.x;
        int v = (i < n) ? cnt[i] : 0;
        buf[threadIdx.x] = v;
        __syncthreads();
        #pragma unroll
        for (int off = 1; off < 256; off <<= 1) {
            int t = (threadIdx.x >= (unsigned)off) ? buf[threadIdx.x - off] : 0;
            __syncthreads();
            buf[threadIdx.x] += t;
            __syncthreads();
        }
        int excl = carry + buf[threadIdx.x] - v;
        if (i < n) { row[i] = excl; cur[i] = excl; }
        __syncthreads();
        if (threadIdx.x == 255) carry += buf[255];
        __syncthreads();
    }
}

__global__ __launch_bounds__(256) void scatter_kernel(
    const int* __restrict__ dst, int E, int* __restrict__ cur, int* __restrict__ csr)
{
    int i = blockIdx.x * 256 + threadIdx.x;
    int n = gridDim.x * 256;
    for (int e = i; e < E; e += n) {
        int pos = atomicAdd(&cur[dst[e]], 1);
        csr[pos] = e;
    }
}

// ---- topic gather: TOPIC_C chunk-waves/node over raw bf16 word feats, unroll-4 ----
__global__ __launch_bounds__(256) void gather_topic(
    const __hip_bfloat16* __restrict__ fw, const float* __restrict__ ew,
    const int* __restrict__ src, const int* __restrict__ csr,
    const int* __restrict__ rowp, const int* __restrict__ cnt,
    float* __restrict__ part, float* __restrict__ part_sumw)
{
    int wid = (blockIdx.x * 256 + (int)threadIdx.x) >> 6;
    int lane = threadIdx.x & 63;
    int node = wid >> 4;
    int chunk = wid & (TOPIC_C - 1);
    if (node >= N_TOPIC) return;
    int start = rowp[node], deg = cnt[node];
    const unsigned short* T = (const unsigned short*)fw;
    float a0 = 0.f, a1 = 0.f, a2 = 0.f, a3 = 0.f, sw = 0.f;
    int j = chunk;
    for (; j + 3 * TOPIC_C < deg; j += 4 * TOPIC_C) {
        int e0 = csr[start + j];
        int e1 = csr[start + j + TOPIC_C];
        int e2 = csr[start + j + 2 * TOPIC_C];
        int e3 = csr[start + j + 3 * TOPIC_C];
        int s0 = src[e0], s1 = src[e1], s2 = src[e2], s3 = src[e3];
        float w0 = ew[e0], w1 = ew[e1], w2 = ew[e2], w3 = ew[e3];
        short4v v0 = *reinterpret_cast<const short4v*>(T + (size_t)s0 * DIM + lane * 4);
        short4v v1 = *reinterpret_cast<const short4v*>(T + (size_t)s1 * DIM + lane * 4);
        short4v v2 = *reinterpret_cast<const short4v*>(T + (size_t)s2 * DIM + lane * 4);
        short4v v3 = *reinterpret_cast<const short4v*>(T + (size_t)s3 * DIM + lane * 4);
        acc4(a0, a1, a2, a3, v0, w0);
        acc4(a0, a1, a2, a3, v1, w1);
        acc4(a0, a1, a2, a3, v2, w2);
        acc4(a0, a1, a2, a3, v3, w3);
        sw += w0 + w1 + w2 + w3;
    }
    for (; j < deg; j += TOPIC_C) {
        int e = csr[start + j];
        int s = src[e];
        float w = ew[e];
        short4v v = *reinterpret_cast<const short4v*>(T + (size_t)s * DIM + lane * 4);
        acc4(a0, a1, a2, a3, v, w);
        sw += w;
    }
    f32x4 r = {a0, a1, a2, a3};
    *reinterpret_cast<f32x4*>(part + ((size_t)chunk * N_TOPIC + node) * DIM + lane * 4) = r;
    if (lane == 0) part_sumw[chunk * N_TOPIC + node] = sw;
}

// reduce partials -> agg (f32, scaled 1/deg) + mw
__global__ __launch_bounds__(256) void topic_reduce(
    const float* __restrict__ part, const float* __restrict__ part_sumw,
    const int* __restrict__ cnt,
    float* __restrict__ agg, float* __restrict__ mw)
{
    int node = blockIdx.x;
    int dim = threadIdx.x;
    float s = 0.f;
    #pragma unroll
    for (int c = 0; c < TOPIC_C; ++c)
        s += part[((size_t)c * N_TOPIC + node) * DIM + dim];
    int d = cnt[node];
    float inv = 1.f / (float)(d > 1 ? d : 1);
    agg[(size_t)node * DIM + dim] = s * inv;
    if (dim == 0) {
        float sw = 0.f;
        #pragma unroll
        for (int c = 0; c < TOPIC_C; ++c) sw += part_sumw[c * N_TOPIC + node];
        mw[node] = sw * inv;
    }
}

// ---- doc gather: one wave per (node, relation), unroll-4, writes f32 agg + mw ----
__global__ __launch_bounds__(256) void gather_doc(
    const __hip_bfloat16* __restrict__ fw, const float* __restrict__ w_wd,
    const int* __restrict__ wd_src, const int* __restrict__ csr_wd,
    const int* __restrict__ row_wd, const int* __restrict__ cnt_wd,
    const __hip_bfloat16* __restrict__ ft, const float* __restrict__ w_td,
    const int* __restrict__ td_src, const int* __restrict__ csr_td,
    const int* __restrict__ row_td, const int* __restrict__ cnt_td,
    float* __restrict__ agg_wd, float* __restrict__ mw_wd,
    float* __restrict__ agg_td, float* __restrict__ mw_td)
{
    int wid = (blockIdx.x * 256 + (int)threadIdx.x) >> 6;
    int lane = threadIdx.x & 63;
    if (wid >= 2 * N_DOC) return;
    int rel = wid >= N_DOC;
    int node = rel ? wid - N_DOC : wid;

    const unsigned short* T = (const unsigned short*)(rel ? ft : fw);
    const float* ew = rel ? w_td : w_wd;
    const int* src  = rel ? td_src : wd_src;
    const int* csr  = rel ? csr_td : csr_wd;
    const int* rowp = rel ? row_td : row_wd;
    const int* cnt  = rel ? cnt_td : cnt_wd;
    float* agg = rel ? agg_td : agg_wd;
    float* mw  = rel ? mw_td : mw_wd;

    int start = rowp[node], deg = cnt[node];
    float a0 = 0.f, a1 = 0.f, a2 = 0.f, a3 = 0.f, sw = 0.f;
    int j = 0;
    for (; j + 4 <= deg; j += 4) {
        int e0 = csr[start + j];
        int e1 = csr[start + j + 1];
        int e2 = csr[start + j + 2];
        int e3 = csr[start + j + 3];
        int s0 = src[e0], s1 = src[e1], s2 = src[e2], s3 = src[e3];
        float w0 = ew[e0], w1 = ew[e1], w2 = ew[e2], w3 = ew[e3];
        short4v v0 = *reinterpret_cast<const short4v*>(T + (size_t)s0 * DIM + lane * 4);
        short4v v1 = *reinterpret_cast<const short4v*>(T + (size_t)s1 * DIM + lane * 4);
        short4v v2 = *reinterpret_cast<const short4v*>(T + (size_t)s2 * DIM + lane * 4);
        short4v v3 = *reinterpret_cast<const short4v*>(T + (size_t)s3 * DIM + lane * 4);
        acc4(a0, a1, a2, a3, v0, w0);
        acc4(a0, a1, a2, a3, v1, w1);
        acc4(a0, a1, a2, a3, v2, w2);
        acc4(a0, a1, a2, a3, v3, w3);
        sw += w0 + w1 + w2 + w3;
    }
    for (; j < deg; ++j) {
        int e = csr[start + j];
        int s = src[e];
        float w = ew[e];
        short4v v = *reinterpret_cast<const short4v*>(T + (size_t)s * DIM + lane * 4);
        acc4(a0, a1, a2, a3, v, w);
        sw += w;
    }
    float inv = 1.f / (float)(deg > 1 ? deg : 1);
    f32x4 r = {a0 * inv, a1 * inv, a2 * inv, a3 * inv};
    *reinterpret_cast<f32x4*>(agg + (size_t)node * DIM + lane * 4) = r;
    if (lane == 0) mw[node] = sw * inv;
}

// ---- h_topic = agg_wt @ Wt^T + bt*mw  (f32 A, bf16 W, f32 out) ----
__global__ __launch_bounds__(256) void gemm_topic_out(
    const float* __restrict__ A,
    const __hip_bfloat16* __restrict__ Wbf,
    const float* __restrict__ bias,
    const float* __restrict__ mw,
    float* __restrict__ out)
{
    const int wave = threadIdx.x >> 6;
    const int lane = threadIdx.x & 63;
    const int m0 = blockIdx.x * 64 + wave * 16;
    if (m0 >= N_TOPIC) return;
    const int lr = lane & 15;
    const int kh = lane >> 4;

    int ar = m0 + lr;
    bf16x8 afrag[8];
    #pragma unroll
    for (int kk = 0; kk < 8; ++kk) {
        const float* ap = A + (size_t)ar * DIM + kk * 32 + kh * 8;
        f32x4 a0v = *reinterpret_cast<const f32x4*>(ap);
        f32x4 a1v = *reinterpret_cast<const f32x4*>(ap + 4);
        bf16x8 fr;
        fr[0] = f2bf(a0v[0]); fr[1] = f2bf(a0v[1]); fr[2] = f2bf(a0v[2]); fr[3] = f2bf(a0v[3]);
        fr[4] = f2bf(a1v[0]); fr[5] = f2bf(a1v[1]); fr[6] = f2bf(a1v[2]); fr[7] = f2bf(a1v[3]);
        afrag[kk] = fr;
    }
    const unsigned short* Wu = (const unsigned short*)Wbf;

    #pragma unroll
    for (int ct = 0; ct < 16; ++ct) {
        f32x4 acc = {0.f, 0.f, 0.f, 0.f};
        #pragma unroll
        for (int kk = 0; kk < 8; ++kk) {
            bf16x8 bfrag = *reinterpret_cast<const bf16x8*>(
                Wu + (size_t)(ct * 16 + lr) * DIM + kk * 32 + kh * 8);
            acc = __builtin_amdgcn_mfma_f32_16x16x32_bf16(afrag[kk], bfrag, acc, 0, 0, 0);
        }
        float bb = bias[ct * 16 + lr];
        #pragma unroll
        for (int j = 0; j < 4; ++j) {
            int row = m0 + kh * 4 + j;
            out[(size_t)row * DIM + ct * 16 + lr] = acc[j] + bb * mw[row];
        }
    }
}

// ---- h_doc = relu(agg_wd@Wd^T + bd*mw_wd + agg_td@Wtd^T + btd*mw_td) ----
__global__ __launch_bounds__(256) void gemm_doc_out(
    const float* __restrict__ A1, const __hip_bfloat16* __restrict__ W1,
    const float* __restrict__ b1, const float* __restrict__ mw1,
    const float* __restrict__ A2, const __hip_bfloat16* __restrict__ W2,
    const float* __restrict__ b2, const float* __restrict__ mw2,
    float* __restrict__ out)
{
    const int wave = threadIdx.x >> 6;
    const int lane = threadIdx.x & 63;
    const int m0 = blockIdx.x * 64 + wave * 16;
    if (m0 >= N_DOC) return;
    const int lr = lane & 15;
    const int kh = lane >> 4;

    int ar = m0 + lr; if (ar > N_DOC - 1) ar = N_DOC - 1;
    bf16x8 af1[8], af2[8];
    #pragma unroll
    for (int kk = 0; kk < 8; ++kk) {
        const float* ap = A1 + (size_t)ar * DIM + kk * 32 + kh * 8;
        f32x4 a0v = *reinterpret_cast<const f32x4*>(ap);
        f32x4 a1v = *reinterpret_cast<const f32x4*>(ap + 4);
        bf16x8 fr;
        fr[0] = f2bf(a0v[0]); fr[1] = f2bf(a0v[1]); fr[2] = f2bf(a0v[2]); fr[3] = f2bf(a0v[3]);
        fr[4] = f2bf(a1v[0]); fr[5] = f2bf(a1v[1]); fr[6] = f2bf(a1v[2]); fr[7] = f2bf(a1v[3]);
        af1[kk] = fr;
        const float* bp = A2 + (size_t)ar * DIM + kk * 32 + kh * 8;
        f32x4 b0v = *reinterpret_cast<const f32x4*>(bp);
        f32x4 b1v = *reinterpret_cast<const f32x4*>(bp + 4);
        bf16x8 fr2;
        fr2[0] = f2bf(b0v[0]); fr2[1] = f2bf(b0v[1]); fr2[2] = f2bf(b0v[2]); fr2[3] = f2bf(b0v[3]);
        fr2[4] = f2bf(b1v[0]); fr2[5] = f2bf(b1v[1]); fr2[6] = f2bf(b1v[2]); fr2[7] = f2bf(b1v[3]);
        af2[kk] = fr2;
    }
    const unsigned short* Wu1 = (const unsigned short*)W1;
    const unsigned short* Wu2 = (const unsigned short*)W2;

    #pragma unroll
    for (int ct = 0; ct < 16; ++ct) {
        f32x4 acc = {0.f, 0.f, 0.f, 0.f};
        #pragma unroll
        for (int kk = 0; kk < 8; ++kk) {
            bf16x8 bf1 = *reinterpret_cast<const bf16x8*>(
                Wu1 + (size_t)(ct * 16 + lr) * DIM + kk * 32 + kh * 8);
            acc = __builtin_amdgcn_mfma_f32_16x16x32_bf16(af1[kk], bf1, acc, 0, 0, 0);
            bf16x8 bf2v = *reinterpret_cast<const bf16x8*>(
                Wu2 + (size_t)(ct * 16 + lr) * DIM + kk * 32 + kh * 8);
            acc = __builtin_amdgcn_mfma_f32_16x16x32_bf16(af2[kk], bf2v, acc, 0, 0, 0);
        }
        float bb1 = b1[ct * 16 + lr];
        float bb2 = b2[ct * 16 + lr];
        #pragma unroll
        for (int j = 0; j < 4; ++j) {
            int row = m0 + kh * 4 + j;
            if (row < N_DOC) {
                float v = acc[j] + bb1 * mw1[row] + bb2 * mw2[row];
                out[(size_t)row * DIM + ct * 16 + lr] = fmaxf(v, 0.f);
            }
        }
    }
}

extern "C" void kernel_launch(void* const* d_in, const int* in_sizes, int n_in,
                              void* d_out, int out_size, void* d_ws, size_t ws_size,
                              hipStream_t stream)
{
    const float* feat_word  = (const float*)d_in[0];
    const float* feat_topic = (const float*)d_in[1];
    /* feat_doc (d_in[2]) unused by the reference output */
    const int* wt_src = (const int*)d_in[3];
    const int* wt_dst = (const int*)d_in[4];
    const int* wd_src = (const int*)d_in[5];
    const int* wd_dst = (const int*)d_in[6];
    const int* td_src = (const int*)d_in[7];
    const int* td_dst = (const int*)d_in[8];
    const float* w_wt = (const float*)d_in[9];
    const float* w_wd = (const float*)d_in[10];
    const float* w_td = (const float*)d_in[11];
    const float* Wt   = (const float*)d_in[12];
    const float* bt   = (const float*)d_in[13];
    const float* Wd   = (const float*)d_in[14];
    const float* bd   = (const float*)d_in[15];
    const float* Wtd  = (const float*)d_in[16];
    const float* btd  = (const float*)d_in[17];

    char* ws = (char*)d_ws;
    // Workspace layout (bytes), ~48.4 MB total:
    __hip_bfloat16* fw = (__hip_bfloat16*)(ws + 0);             // 30000*256*2 = 15,360,000
    __hip_bfloat16* ft = (__hip_bfloat16*)(ws + 15360000);      // 262,144
    __hip_bfloat16* Wbf_t  = (__hip_bfloat16*)(ws + 15622144);  // 131,072
    __hip_bfloat16* Wbf_d  = (__hip_bfloat16*)(ws + 15753216);  // 131,072
    __hip_bfloat16* Wbf_td = (__hip_bfloat16*)(ws + 15884288);  // 131,072 -> 16,015,360
    float* agg_wt = (float*)(ws + 16015360);                    // 512*256*4 = 524,288
    float* agg_wd = (float*)(ws + 16539648);                    // 10,240,000
    float* agg_td = (float*)(ws + 26779648);                    // 10,240,000 -> 37,019,648
    float* part_topic = (float*)(ws + 37019648);                // 16*512*256*4 = 8,388,608
    float* part_sumw  = (float*)(ws + 45408256);                // 16*512*4 = 32,768
    float* mw_wt = (float*)(ws + 45441024);                     // 2,048
    float* mw_wd = (float*)(ws + 45443072);                     // 40,000
    float* mw_td = (float*)(ws + 45483072);                     // 40,000 -> 45,523,072
    int* cnt_wt = (int*)(ws + 45523072);                        // 2,048   } zero region
    int* cnt_wd = (int*)(ws + 45525120);                        // 40,000  }
    int* cnt_td = (int*)(ws + 45565120);                        // 40,000  } -> 45,605,120
    int* row_wt = (int*)(ws + 45605120);                        // 2,048
    int* row_wd = (int*)(ws + 45607168);                        // 40,000
    int* row_td = (int*)(ws + 45647168);                        // 40,000
    int* cur_wt = (int*)(ws + 45687168);                        // 2,048
    int* cur_wd = (int*)(ws + 45689216);                        // 40,000
    int* cur_td = (int*)(ws + 45729216);                        // 40,000
    int* csr_wt = (int*)(ws + 45769216);                        // 1,048,576
    int* csr_wd = (int*)(ws + 46817792);                        // 1,048,576
    int* csr_td = (int*)(ws + 47866368);                        // 524,288 -> 48,390,656

    // zero histogram counters only
    hipMemsetAsync(ws + 45523072, 0, 82048, stream);

    // word passthrough (independent of everything else)
    float* out = (float*)d_out;
    hipMemcpyAsync(out, feat_word, (size_t)N_WORD * DIM * sizeof(float),
                   hipMemcpyDeviceToDevice, stream);

    // casts
    cvt_w3<<<(DIM * DIM + 255) / 256, 256, 0, stream>>>(Wt, Wd, Wtd, Wbf_t, Wbf_d, Wbf_td);
    cvt_f32_bf16<<<(N_WORD * DIM / 8 + 255) / 256, 256, 0, stream>>>(feat_word, fw, N_WORD * DIM / 8);
    cvt_f32_bf16<<<(N_TOPIC * DIM / 8 + 255) / 256, 256, 0, stream>>>(feat_topic, ft, N_TOPIC * DIM / 8);

    // CSR build
    hist_kernel<<<256, 256, 0, stream>>>(wt_dst, E_WT, cnt_wt);
    hist_kernel<<<256, 256, 0, stream>>>(wd_dst, E_WD, cnt_wd);
    hist_kernel<<<128, 256, 0, stream>>>(td_dst, E_TD, cnt_td);
    exscan_kernel<<<1, 256, 0, stream>>>(cnt_wt, row_wt, cur_wt, N_TOPIC);
    exscan_kernel<<<1, 256, 0, stream>>>(cnt_wd, row_wd, cur_wd, N_DOC);
    exscan_kernel<<<1, 256, 0, stream>>>(cnt_td, row_td, cur_td, N_DOC);
    scatter_kernel<<<256, 256, 0, stream>>>(wt_dst, E_WT, cur_wt, csr_wt);
    scatter_kernel<<<256, 256, 0, stream>>>(wd_dst, E_WD, cur_wd, csr_wd);
    scatter_kernel<<<128, 256, 0, stream>>>(td_dst, E_TD, cur_td, csr_td);

    // aggregate raw features (mean with edge weights), then transform
    gather_topic<<<(N_TOPIC * TOPIC_C) / 4, 256, 0, stream>>>(
        fw, w_wt, wt_src, csr_wt, row_wt, cnt_wt, part_topic, part_sumw);
    topic_reduce<<<N_TOPIC, 256, 0, stream>>>(
        part_topic, part_sumw, cnt_wt, agg_wt, mw_wt);
    gather_doc<<<(2 * N_DOC + 3) / 4, 256, 0, stream>>>(
        fw, w_wd, wd_src, csr_wd, row_wd, cnt_wd,
        ft, w_td, td_src, csr_td, row_td, cnt_td,
        agg_wd, mw_wd, agg_td, mw_td);

    // post-aggregation linears straight to output
    gemm_topic_out<<<N_TOPIC / 64, 256, 0, stream>>>(
        agg_wt, Wbf_t, bt, mw_wt, out + (size_t)N_WORD * DIM);
    gemm_doc_out<<<(N_DOC + 63) / 64, 256, 0, stream>>>(
        agg_wd, Wbf_d, bd, mw_wd, agg_td, Wbf_td, btd, mw_td,
        out + (size_t)(N_WORD + N_TOPIC) * DIM);
}

// Round 5
// 299.752 us; speedup vs baseline: 8.6172x; 1.5823x over previous
//
#include <hip/hip_runtime.h>
#include <hip/hip_bf16.h>

#define N_WORD  30000
#define N_TOPIC 512
#define N_DOC   10000
#define E_WT    262144
#define E_WD    262144
#define E_TD    131072
#define DIM     256
#define TOPIC_C 16   // chunk-waves per topic node
#define WT_BLOCKS 16 // blocks for LDS-binned wt CSR build

typedef __attribute__((ext_vector_type(8))) short bf16x8;
typedef __attribute__((ext_vector_type(4))) float f32x4;
typedef __attribute__((ext_vector_type(4))) short short4v;

__device__ __forceinline__ float bf2f(unsigned short u) {
    unsigned int v = ((unsigned int)u) << 16;
    float f;
    __builtin_memcpy(&f, &v, 4);
    return f;
}
__device__ __forceinline__ short f2bf(float f) {
    __hip_bfloat16 h = __float2bfloat16(f);   // RNE
    short s;
    __builtin_memcpy(&s, &h, 2);
    return s;
}
__device__ __forceinline__ void acc4(float& a0, float& a1, float& a2, float& a3,
                                     short4v v, float w) {
    a0 += bf2f((unsigned short)v.x) * w;
    a1 += bf2f((unsigned short)v.y) * w;
    a2 += bf2f((unsigned short)v.z) * w;
    a3 += bf2f((unsigned short)v.w) * w;
}

// ---- f32 -> bf16 cast, 8 elems/thread ----
__global__ __launch_bounds__(256) void cvt_f32_bf16(
    const float* __restrict__ in, __hip_bfloat16* __restrict__ out, int n8)
{
    int i = blockIdx.x * 256 + threadIdx.x;
    if (i >= n8) return;
    f32x4 a = *reinterpret_cast<const f32x4*>(in + (size_t)i * 8);
    f32x4 b = *reinterpret_cast<const f32x4*>(in + (size_t)i * 8 + 4);
    bf16x8 r;
    r[0] = f2bf(a[0]); r[1] = f2bf(a[1]); r[2] = f2bf(a[2]); r[3] = f2bf(a[3]);
    r[4] = f2bf(b[0]); r[5] = f2bf(b[1]); r[6] = f2bf(b[2]); r[7] = f2bf(b[3]);
    *reinterpret_cast<bf16x8*>((unsigned short*)out + (size_t)i * 8) = r;
}

// ---- convert the three f32 weight matrices to bf16 ----
__global__ __launch_bounds__(256) void cvt_w3(
    const float* __restrict__ a, const float* __restrict__ b, const float* __restrict__ c,
    __hip_bfloat16* __restrict__ oa, __hip_bfloat16* __restrict__ ob, __hip_bfloat16* __restrict__ oc)
{
    int i = blockIdx.x * 256 + threadIdx.x;
    if (i >= DIM * DIM) return;
    oa[i] = __float2bfloat16(a[i]);
    ob[i] = __float2bfloat16(b[i]);
    oc[i] = __float2bfloat16(c[i]);
}

// ---- CSR build: wd/td (low per-address contention -> plain global atomics) ----
__global__ __launch_bounds__(256) void hist_kernel(
    const int* __restrict__ dst, int E, int* __restrict__ cnt)
{
    int i = blockIdx.x * 256 + threadIdx.x;
    int n = gridDim.x * 256;
    for (int e = i; e < E; e += n) atomicAdd(&cnt[dst[e]], 1);
}

__global__ __launch_bounds__(256) void scatter_kernel(
    const int* __restrict__ dst, int E, int* __restrict__ cur, int* __restrict__ csr)
{
    int i = blockIdx.x * 256 + threadIdx.x;
    int n = gridDim.x * 256;
    for (int e = i; e < E; e += n) {
        int pos = atomicAdd(&cur[dst[e]], 1);
        csr[pos] = e;
    }
}

// ---- CSR build: wt (512 counters -> LDS binning; global atomic depth 512 -> 16) ----
__global__ __launch_bounds__(256) void hist_topic(
    const int* __restrict__ dst, int* __restrict__ cnt)
{
    __shared__ int lc[N_TOPIC];
    for (int i = threadIdx.x; i < N_TOPIC; i += 256) lc[i] = 0;
    __syncthreads();
    const int per = E_WT / WT_BLOCKS;
    const int s = blockIdx.x * per;
    for (int i = s + (int)threadIdx.x; i < s + per; i += 256)
        atomicAdd(&lc[dst[i]], 1);
    __syncthreads();
    for (int i = threadIdx.x; i < N_TOPIC; i += 256) {
        int v = lc[i];
        if (v) atomicAdd(&cnt[i], v);
    }
}

__global__ __launch_bounds__(256) void scatter_topic(
    const int* __restrict__ dst, int* __restrict__ cur, int* __restrict__ csr)
{
    __shared__ int lc[N_TOPIC];
    __shared__ int lbase[N_TOPIC];
    for (int i = threadIdx.x; i < N_TOPIC; i += 256) lc[i] = 0;
    __syncthreads();
    const int per = E_WT / WT_BLOCKS;
    const int s = blockIdx.x * per;
    for (int i = s + (int)threadIdx.x; i < s + per; i += 256)
        atomicAdd(&lc[dst[i]], 1);
    __syncthreads();
    for (int i = threadIdx.x; i < N_TOPIC; i += 256) {
        int v = lc[i];
        lbase[i] = v ? atomicAdd(&cur[i], v) : 0;
        lc[i] = 0;   // reuse as local cursor (each i touched by exactly one thread)
    }
    __syncthreads();
    for (int i = s + (int)threadIdx.x; i < s + per; i += 256) {
        int d = dst[i];
        int pos = atomicAdd(&lc[d], 1);
        csr[lbase[d] + pos] = i;
    }
}

// ---- single-block exclusive scan: K elems/thread in registers, wave shuffle scan ----
template<int K>
__global__ __launch_bounds__(256) void exscan_fast(
    const int* __restrict__ cnt, int* __restrict__ row, int* __restrict__ cur, int n)
{
    __shared__ int wsum[4];
    const int t = threadIdx.x;
    const int lane = t & 63, wid = t >> 6;
    int c[K];
    const int base = t * K;
    int tot = 0;
    #pragma unroll
    for (int k = 0; k < K; ++k) {
        int idx = base + k;
        c[k] = (idx < n) ? cnt[idx] : 0;
        tot += c[k];
    }
    int inc = tot;                       // wave-inclusive scan of per-thread totals
    #pragma unroll
    for (int off = 1; off < 64; off <<= 1) {
        int u = __shfl_up(inc, off, 64);
        if (lane >= off) inc += u;
    }
    if (lane == 63) wsum[wid] = inc;
    __syncthreads();
    int woff = 0;
    for (int w = 0; w < wid; ++w) woff += wsum[w];
    int run = woff + inc - tot;          // exclusive prefix for this thread's range
    #pragma unroll
    for (int k = 0; k < K; ++k) {
        int idx = base + k;
        if (idx < n) { row[idx] = run; cur[idx] = run; }
        run += c[k];
    }
}

// ---- topic gather: TOPIC_C chunk-waves/node over raw bf16 word feats, unroll-4 ----
__global__ __launch_bounds__(256) void gather_topic(
    const __hip_bfloat16* __restrict__ fw, const float* __restrict__ ew,
    const int* __restrict__ src, const int* __restrict__ csr,
    const int* __restrict__ rowp, const int* __restrict__ cnt,
    float* __restrict__ part, float* __restrict__ part_sumw)
{
    int wid = (blockIdx.x * 256 + (int)threadIdx.x) >> 6;
    int lane = threadIdx.x & 63;
    int node = wid >> 4;
    int chunk = wid & (TOPIC_C - 1);
    if (node >= N_TOPIC) return;
    int start = rowp[node], deg = cnt[node];
    const unsigned short* T = (const unsigned short*)fw;
    float a0 = 0.f, a1 = 0.f, a2 = 0.f, a3 = 0.f, sw = 0.f;
    int j = chunk;
    for (; j + 3 * TOPIC_C < deg; j += 4 * TOPIC_C) {
        int e0 = csr[start + j];
        int e1 = csr[start + j + TOPIC_C];
        int e2 = csr[start + j + 2 * TOPIC_C];
        int e3 = csr[start + j + 3 * TOPIC_C];
        int s0 = src[e0], s1 = src[e1], s2 = src[e2], s3 = src[e3];
        float w0 = ew[e0], w1 = ew[e1], w2 = ew[e2], w3 = ew[e3];
        short4v v0 = *reinterpret_cast<const short4v*>(T + (size_t)s0 * DIM + lane * 4);
        short4v v1 = *reinterpret_cast<const short4v*>(T + (size_t)s1 * DIM + lane * 4);
        short4v v2 = *reinterpret_cast<const short4v*>(T + (size_t)s2 * DIM + lane * 4);
        short4v v3 = *reinterpret_cast<const short4v*>(T + (size_t)s3 * DIM + lane * 4);
        acc4(a0, a1, a2, a3, v0, w0);
        acc4(a0, a1, a2, a3, v1, w1);
        acc4(a0, a1, a2, a3, v2, w2);
        acc4(a0, a1, a2, a3, v3, w3);
        sw += w0 + w1 + w2 + w3;
    }
    for (; j < deg; j += TOPIC_C) {
        int e = csr[start + j];
        int s = src[e];
        float w = ew[e];
        short4v v = *reinterpret_cast<const short4v*>(T + (size_t)s * DIM + lane * 4);
        acc4(a0, a1, a2, a3, v, w);
        sw += w;
    }
    f32x4 r = {a0, a1, a2, a3};
    *reinterpret_cast<f32x4*>(part + ((size_t)chunk * N_TOPIC + node) * DIM + lane * 4) = r;
    if (lane == 0) part_sumw[chunk * N_TOPIC + node] = sw;
}

// reduce partials -> agg (f32, scaled 1/deg) + mw
__global__ __launch_bounds__(256) void topic_reduce(
    const float* __restrict__ part, const float* __restrict__ part_sumw,
    const int* __restrict__ cnt,
    float* __restrict__ agg, float* __restrict__ mw)
{
    int node = blockIdx.x;
    int dim = threadIdx.x;
    float s = 0.f;
    #pragma unroll
    for (int c = 0; c < TOPIC_C; ++c)
        s += part[((size_t)c * N_TOPIC + node) * DIM + dim];
    int d = cnt[node];
    float inv = 1.f / (float)(d > 1 ? d : 1);
    agg[(size_t)node * DIM + dim] = s * inv;
    if (dim == 0) {
        float sw = 0.f;
        #pragma unroll
        for (int c = 0; c < TOPIC_C; ++c) sw += part_sumw[c * N_TOPIC + node];
        mw[node] = sw * inv;
    }
}

// ---- doc gather: one wave per (node, relation), unroll-4, writes f32 agg + mw ----
__global__ __launch_bounds__(256) void gather_doc(
    const __hip_bfloat16* __restrict__ fw, const float* __restrict__ w_wd,
    const int* __restrict__ wd_src, const int* __restrict__ csr_wd,
    const int* __restrict__ row_wd, const int* __restrict__ cnt_wd,
    const __hip_bfloat16* __restrict__ ft, const float* __restrict__ w_td,
    const int* __restrict__ td_src, const int* __restrict__ csr_td,
    const int* __restrict__ row_td, const int* __restrict__ cnt_td,
    float* __restrict__ agg_wd, float* __restrict__ mw_wd,
    float* __restrict__ agg_td, float* __restrict__ mw_td)
{
    int wid = (blockIdx.x * 256 + (int)threadIdx.x) >> 6;
    int lane = threadIdx.x & 63;
    if (wid >= 2 * N_DOC) return;
    int rel = wid >= N_DOC;
    int node = rel ? wid - N_DOC : wid;

    const unsigned short* T = (const unsigned short*)(rel ? ft : fw);
    const float* ew = rel ? w_td : w_wd;
    const int* src  = rel ? td_src : wd_src;
    const int* csr  = rel ? csr_td : csr_wd;
    const int* rowp = rel ? row_td : row_wd;
    const int* cnt  = rel ? cnt_td : cnt_wd;
    float* agg = rel ? agg_td : agg_wd;
    float* mw  = rel ? mw_td : mw_wd;

    int start = rowp[node], deg = cnt[node];
    float a0 = 0.f, a1 = 0.f, a2 = 0.f, a3 = 0.f, sw = 0.f;
    int j = 0;
    for (; j + 4 <= deg; j += 4) {
        int e0 = csr[start + j];
        int e1 = csr[start + j + 1];
        int e2 = csr[start + j + 2];
        int e3 = csr[start + j + 3];
        int s0 = src[e0], s1 = src[e1], s2 = src[e2], s3 = src[e3];
        float w0 = ew[e0], w1 = ew[e1], w2 = ew[e2], w3 = ew[e3];
        short4v v0 = *reinterpret_cast<const short4v*>(T + (size_t)s0 * DIM + lane * 4);
        short4v v1 = *reinterpret_cast<const short4v*>(T + (size_t)s1 * DIM + lane * 4);
        short4v v2 = *reinterpret_cast<const short4v*>(T + (size_t)s2 * DIM + lane * 4);
        short4v v3 = *reinterpret_cast<const short4v*>(T + (size_t)s3 * DIM + lane * 4);
        acc4(a0, a1, a2, a3, v0, w0);
        acc4(a0, a1, a2, a3, v1, w1);
        acc4(a0, a1, a2, a3, v2, w2);
        acc4(a0, a1, a2, a3, v3, w3);
        sw += w0 + w1 + w2 + w3;
    }
    for (; j < deg; ++j) {
        int e = csr[start + j];
        int s = src[e];
        float w = ew[e];
        short4v v = *reinterpret_cast<const short4v*>(T + (size_t)s * DIM + lane * 4);
        acc4(a0, a1, a2, a3, v, w);
        sw += w;
    }
    float inv = 1.f / (float)(deg > 1 ? deg : 1);
    f32x4 r = {a0 * inv, a1 * inv, a2 * inv, a3 * inv};
    *reinterpret_cast<f32x4*>(agg + (size_t)node * DIM + lane * 4) = r;
    if (lane == 0) mw[node] = sw * inv;
}

// ---- h_topic = agg_wt @ Wt^T + bt*mw  (f32 A, bf16 W, f32 out) ----
__global__ __launch_bounds__(256) void gemm_topic_out(
    const float* __restrict__ A,
    const __hip_bfloat16* __restrict__ Wbf,
    const float* __restrict__ bias,
    const float* __restrict__ mw,
    float* __restrict__ out)
{
    const int wave = threadIdx.x >> 6;
    const int lane = threadIdx.x & 63;
    const int m0 = blockIdx.x * 64 + wave * 16;
    if (m0 >= N_TOPIC) return;
    const int lr = lane & 15;
    const int kh = lane >> 4;

    int ar = m0 + lr;
    bf16x8 afrag[8];
    #pragma unroll
    for (int kk = 0; kk < 8; ++kk) {
        const float* ap = A + (size_t)ar * DIM + kk * 32 + kh * 8;
        f32x4 a0v = *reinterpret_cast<const f32x4*>(ap);
        f32x4 a1v = *reinterpret_cast<const f32x4*>(ap + 4);
        bf16x8 fr;
        fr[0] = f2bf(a0v[0]); fr[1] = f2bf(a0v[1]); fr[2] = f2bf(a0v[2]); fr[3] = f2bf(a0v[3]);
        fr[4] = f2bf(a1v[0]); fr[5] = f2bf(a1v[1]); fr[6] = f2bf(a1v[2]); fr[7] = f2bf(a1v[3]);
        afrag[kk] = fr;
    }
    const unsigned short* Wu = (const unsigned short*)Wbf;

    #pragma unroll
    for (int ct = 0; ct < 16; ++ct) {
        f32x4 acc = {0.f, 0.f, 0.f, 0.f};
        #pragma unroll
        for (int kk = 0; kk < 8; ++kk) {
            bf16x8 bfrag = *reinterpret_cast<const bf16x8*>(
                Wu + (size_t)(ct * 16 + lr) * DIM + kk * 32 + kh * 8);
            acc = __builtin_amdgcn_mfma_f32_16x16x32_bf16(afrag[kk], bfrag, acc, 0, 0, 0);
        }
        float bb = bias[ct * 16 + lr];
        #pragma unroll
        for (int j = 0; j < 4; ++j) {
            int row = m0 + kh * 4 + j;
            out[(size_t)row * DIM + ct * 16 + lr] = acc[j] + bb * mw[row];
        }
    }
}

// ---- h_doc = relu(agg_wd@Wd^T + bd*mw_wd + agg_td@Wtd^T + btd*mw_td) ----
__global__ __launch_bounds__(256) void gemm_doc_out(
    const float* __restrict__ A1, const __hip_bfloat16* __restrict__ W1,
    const float* __restrict__ b1, const float* __restrict__ mw1,
    const float* __restrict__ A2, const __hip_bfloat16* __restrict__ W2,
    const float* __restrict__ b2, const float* __restrict__ mw2,
    float* __restrict__ out)
{
    const int wave = threadIdx.x >> 6;
    const int lane = threadIdx.x & 63;
    const int m0 = blockIdx.x * 64 + wave * 16;
    if (m0 >= N_DOC) return;
    const int lr = lane & 15;
    const int kh = lane >> 4;

    int ar = m0 + lr; if (ar > N_DOC - 1) ar = N_DOC - 1;
    bf16x8 af1[8], af2[8];
    #pragma unroll
    for (int kk = 0; kk < 8; ++kk) {
        const float* ap = A1 + (size_t)ar * DIM + kk * 32 + kh * 8;
        f32x4 a0v = *reinterpret_cast<const f32x4*>(ap);
        f32x4 a1v = *reinterpret_cast<const f32x4*>(ap + 4);
        bf16x8 fr;
        fr[0] = f2bf(a0v[0]); fr[1] = f2bf(a0v[1]); fr[2] = f2bf(a0v[2]); fr[3] = f2bf(a0v[3]);
        fr[4] = f2bf(a1v[0]); fr[5] = f2bf(a1v[1]); fr[6] = f2bf(a1v[2]); fr[7] = f2bf(a1v[3]);
        af1[kk] = fr;
        const float* bp = A2 + (size_t)ar * DIM + kk * 32 + kh * 8;
        f32x4 b0v = *reinterpret_cast<const f32x4*>(bp);
        f32x4 b1v = *reinterpret_cast<const f32x4*>(bp + 4);
        bf16x8 fr2;
        fr2[0] = f2bf(b0v[0]); fr2[1] = f2bf(b0v[1]); fr2[2] = f2bf(b0v[2]); fr2[3] = f2bf(b0v[3]);
        fr2[4] = f2bf(b1v[0]); fr2[5] = f2bf(b1v[1]); fr2[6] = f2bf(b1v[2]); fr2[7] = f2bf(b1v[3]);
        af2[kk] = fr2;
    }
    const unsigned short* Wu1 = (const unsigned short*)W1;
    const unsigned short* Wu2 = (const unsigned short*)W2;

    #pragma unroll
    for (int ct = 0; ct < 16; ++ct) {
        f32x4 acc = {0.f, 0.f, 0.f, 0.f};
        #pragma unroll
        for (int kk = 0; kk < 8; ++kk) {
            bf16x8 bf1 = *reinterpret_cast<const bf16x8*>(
                Wu1 + (size_t)(ct * 16 + lr) * DIM + kk * 32 + kh * 8);
            acc = __builtin_amdgcn_mfma_f32_16x16x32_bf16(af1[kk], bf1, acc, 0, 0, 0);
            bf16x8 bf2v = *reinterpret_cast<const bf16x8*>(
                Wu2 + (size_t)(ct * 16 + lr) * DIM + kk * 32 + kh * 8);
            acc = __builtin_amdgcn_mfma_f32_16x16x32_bf16(af2[kk], bf2v, acc, 0, 0, 0);
        }
        float bb1 = b1[ct * 16 + lr];
        float bb2 = b2[ct * 16 + lr];
        #pragma unroll
        for (int j = 0; j < 4; ++j) {
            int row = m0 + kh * 4 + j;
            if (row < N_DOC) {
                float v = acc[j] + bb1 * mw1[row] + bb2 * mw2[row];
                out[(size_t)row * DIM + ct * 16 + lr] = fmaxf(v, 0.f);
            }
        }
    }
}

extern "C" void kernel_launch(void* const* d_in, const int* in_sizes, int n_in,
                              void* d_out, int out_size, void* d_ws, size_t ws_size,
                              hipStream_t stream)
{
    const float* feat_word  = (const float*)d_in[0];
    const float* feat_topic = (const float*)d_in[1];
    /* feat_doc (d_in[2]) unused by the reference output */
    const int* wt_src = (const int*)d_in[3];
    const int* wt_dst = (const int*)d_in[4];
    const int* wd_src = (const int*)d_in[5];
    const int* wd_dst = (const int*)d_in[6];
    const int* td_src = (const int*)d_in[7];
    const int* td_dst = (const int*)d_in[8];
    const float* w_wt = (const float*)d_in[9];
    const float* w_wd = (const float*)d_in[10];
    const float* w_td = (const float*)d_in[11];
    const float* Wt   = (const float*)d_in[12];
    const float* bt   = (const float*)d_in[13];
    const float* Wd   = (const float*)d_in[14];
    const float* bd   = (const float*)d_in[15];
    const float* Wtd  = (const float*)d_in[16];
    const float* btd  = (const float*)d_in[17];

    char* ws = (char*)d_ws;
    // Workspace layout (bytes), ~48.4 MB total:
    __hip_bfloat16* fw = (__hip_bfloat16*)(ws + 0);             // 30000*256*2 = 15,360,000
    __hip_bfloat16* ft = (__hip_bfloat16*)(ws + 15360000);      // 262,144
    __hip_bfloat16* Wbf_t  = (__hip_bfloat16*)(ws + 15622144);  // 131,072
    __hip_bfloat16* Wbf_d  = (__hip_bfloat16*)(ws + 15753216);  // 131,072
    __hip_bfloat16* Wbf_td = (__hip_bfloat16*)(ws + 15884288);  // 131,072 -> 16,015,360
    float* agg_wt = (float*)(ws + 16015360);                    // 512*256*4 = 524,288
    float* agg_wd = (float*)(ws + 16539648);                    // 10,240,000
    float* agg_td = (float*)(ws + 26779648);                    // 10,240,000 -> 37,019,648
    float* part_topic = (float*)(ws + 37019648);                // 16*512*256*4 = 8,388,608
    float* part_sumw  = (float*)(ws + 45408256);                // 16*512*4 = 32,768
    float* mw_wt = (float*)(ws + 45441024);                     // 2,048
    float* mw_wd = (float*)(ws + 45443072);                     // 40,000
    float* mw_td = (float*)(ws + 45483072);                     // 40,000 -> 45,523,072
    int* cnt_wt = (int*)(ws + 45523072);                        // 2,048   } zero region
    int* cnt_wd = (int*)(ws + 45525120);                        // 40,000  }
    int* cnt_td = (int*)(ws + 45565120);                        // 40,000  } -> 45,605,120
    int* row_wt = (int*)(ws + 45605120);                        // 2,048
    int* row_wd = (int*)(ws + 45607168);                        // 40,000
    int* row_td = (int*)(ws + 45647168);                        // 40,000
    int* cur_wt = (int*)(ws + 45687168);                        // 2,048
    int* cur_wd = (int*)(ws + 45689216);                        // 40,000
    int* cur_td = (int*)(ws + 45729216);                        // 40,000
    int* csr_wt = (int*)(ws + 45769216);                        // 1,048,576
    int* csr_wd = (int*)(ws + 46817792);                        // 1,048,576
    int* csr_td = (int*)(ws + 47866368);                        // 524,288 -> 48,390,656

    // zero histogram counters only
    hipMemsetAsync(ws + 45523072, 0, 82048, stream);

    // word passthrough (independent of everything else)
    float* out = (float*)d_out;
    hipMemcpyAsync(out, feat_word, (size_t)N_WORD * DIM * sizeof(float),
                   hipMemcpyDeviceToDevice, stream);

    // casts
    cvt_w3<<<(DIM * DIM + 255) / 256, 256, 0, stream>>>(Wt, Wd, Wtd, Wbf_t, Wbf_d, Wbf_td);
    cvt_f32_bf16<<<(N_WORD * DIM / 8 + 255) / 256, 256, 0, stream>>>(feat_word, fw, N_WORD * DIM / 8);
    cvt_f32_bf16<<<(N_TOPIC * DIM / 8 + 255) / 256, 256, 0, stream>>>(feat_topic, ft, N_TOPIC * DIM / 8);

    // CSR build: wt via LDS binning (512 counters), wd/td via global atomics
    hist_topic<<<WT_BLOCKS, 256, 0, stream>>>(wt_dst, cnt_wt);
    hist_kernel<<<256, 256, 0, stream>>>(wd_dst, E_WD, cnt_wd);
    hist_kernel<<<128, 256, 0, stream>>>(td_dst, E_TD, cnt_td);
    exscan_fast<2><<<1, 256, 0, stream>>>(cnt_wt, row_wt, cur_wt, N_TOPIC);
    exscan_fast<40><<<1, 256, 0, stream>>>(cnt_wd, row_wd, cur_wd, N_DOC);
    exscan_fast<40><<<1, 256, 0, stream>>>(cnt_td, row_td, cur_td, N_DOC);
    scatter_topic<<<WT_BLOCKS, 256, 0, stream>>>(wt_dst, cur_wt, csr_wt);
    scatter_kernel<<<256, 256, 0, stream>>>(wd_dst, E_WD, cur_wd, csr_wd);
    scatter_kernel<<<128, 256, 0, stream>>>(td_dst, E_TD, cur_td, csr_td);

    // aggregate raw features (mean with edge weights), then transform
    gather_topic<<<(N_TOPIC * TOPIC_C) / 4, 256, 0, stream>>>(
        fw, w_wt, wt_src, csr_wt, row_wt, cnt_wt, part_topic, part_sumw);
    topic_reduce<<<N_TOPIC, 256, 0, stream>>>(
        part_topic, part_sumw, cnt_wt, agg_wt, mw_wt);
    gather_doc<<<(2 * N_DOC + 3) / 4, 256, 0, stream>>>(
        fw, w_wd, wd_src, csr_wd, row_wd, cnt_wd,
        ft, w_td, td_src, csr_td, row_td, cnt_td,
        agg_wd, mw_wd, agg_td, mw_td);

    // post-aggregation linears straight to output
    gemm_topic_out<<<N_TOPIC / 64, 256, 0, stream>>>(
        agg_wt, Wbf_t, bt, mw_wt, out + (size_t)N_WORD * DIM);
    gemm_doc_out<<<(N_DOC + 63) / 64, 256, 0, stream>>>(
        agg_wd, Wbf_d, bd, mw_wd, agg_td, Wbf_td, btd, mw_td,
        out + (size_t)(N_WORD + N_TOPIC) * DIM);
}

// Round 6
// 182.888 us; speedup vs baseline: 14.1236x; 1.6390x over previous
//
#include <hip/hip_runtime.h>
#include <hip/hip_bf16.h>

#define N_WORD  30000
#define N_TOPIC 512
#define N_DOC   10000
#define E_WT    262144
#define E_WD    262144
#define E_TD    131072
#define DIM     256
#define TOPIC_C 16   // chunk-waves per topic node
#define WT_BLOCKS 16 // LDS-binned wt CSR build blocks

typedef __attribute__((ext_vector_type(8))) short bf16x8;
typedef __attribute__((ext_vector_type(4))) float f32x4;
typedef __attribute__((ext_vector_type(4))) short short4v;

__device__ __forceinline__ float bf2f(unsigned short u) {
    unsigned int v = ((unsigned int)u) << 16;
    float f;
    __builtin_memcpy(&f, &v, 4);
    return f;
}
__device__ __forceinline__ short f2bf(float f) {
    __hip_bfloat16 h = __float2bfloat16(f);   // RNE
    short s;
    __builtin_memcpy(&s, &h, 2);
    return s;
}
__device__ __forceinline__ void acc4(float& a0, float& a1, float& a2, float& a3,
                                     short4v v, float w) {
    a0 += bf2f((unsigned short)v.x) * w;
    a1 += bf2f((unsigned short)v.y) * w;
    a2 += bf2f((unsigned short)v.z) * w;
    a3 += bf2f((unsigned short)v.w) * w;
}

// ---- fused casts: word (f32 copy + bf16), topic, 3x W. 8 elems/thread ----
#define G_WORD  960000              // 30000*256/8
#define G_TOPIC 16384               // 512*256/8
#define G_W     8192                // 256*256/8
__global__ __launch_bounds__(256) void cvt_all(
    const float* __restrict__ feat_word, const float* __restrict__ feat_topic,
    const float* __restrict__ Wt, const float* __restrict__ Wd, const float* __restrict__ Wtd,
    float* __restrict__ out_word,
    __hip_bfloat16* __restrict__ fw, __hip_bfloat16* __restrict__ ft,
    __hip_bfloat16* __restrict__ wbt, __hip_bfloat16* __restrict__ wbd,
    __hip_bfloat16* __restrict__ wbtd)
{
    int i = blockIdx.x * 256 + threadIdx.x;
    const float* src;
    unsigned short* dst;
    int local;
    bool copy = false;
    if (i < G_WORD) { src = feat_word; local = i; dst = (unsigned short*)fw; copy = true; }
    else if (i < G_WORD + G_TOPIC) { src = feat_topic; local = i - G_WORD; dst = (unsigned short*)ft; }
    else if (i < G_WORD + G_TOPIC + G_W) { src = Wt; local = i - G_WORD - G_TOPIC; dst = (unsigned short*)wbt; }
    else if (i < G_WORD + G_TOPIC + 2 * G_W) { src = Wd; local = i - G_WORD - G_TOPIC - G_W; dst = (unsigned short*)wbd; }
    else { src = Wtd; local = i - G_WORD - G_TOPIC - 2 * G_W; dst = (unsigned short*)wbtd; }

    f32x4 a = *reinterpret_cast<const f32x4*>(src + (size_t)local * 8);
    f32x4 b = *reinterpret_cast<const f32x4*>(src + (size_t)local * 8 + 4);
    if (copy) {
        *reinterpret_cast<f32x4*>(out_word + (size_t)local * 8) = a;
        *reinterpret_cast<f32x4*>(out_word + (size_t)local * 8 + 4) = b;
    }
    bf16x8 r;
    r[0] = f2bf(a[0]); r[1] = f2bf(a[1]); r[2] = f2bf(a[2]); r[3] = f2bf(a[3]);
    r[4] = f2bf(b[0]); r[5] = f2bf(b[1]); r[6] = f2bf(b[2]); r[7] = f2bf(b[3]);
    *reinterpret_cast<bf16x8*>(dst + (size_t)local * 8) = r;
}
#define CVT_TOTAL (G_WORD + G_TOPIC + 3 * G_W)   // 1,000,960 -> 3910 blocks exactly

// ---- fused histograms: blocks 0-15 wt (LDS-binned), 16-79 wd, 80-111 td ----
__global__ __launch_bounds__(256) void hist_all(
    const int* __restrict__ wt_dst, const int* __restrict__ wd_dst, const int* __restrict__ td_dst,
    int* __restrict__ cnt_wt, int* __restrict__ cnt_wd, int* __restrict__ cnt_td)
{
    __shared__ int lc[N_TOPIC];
    int b = blockIdx.x;
    if (b < WT_BLOCKS) {
        for (int i = threadIdx.x; i < N_TOPIC; i += 256) lc[i] = 0;
        __syncthreads();
        const int per = E_WT / WT_BLOCKS;
        const int s = b * per;
        for (int i = s + (int)threadIdx.x; i < s + per; i += 256)
            atomicAdd(&lc[wt_dst[i]], 1);
        __syncthreads();
        for (int i = threadIdx.x; i < N_TOPIC; i += 256) {
            int v = lc[i];
            if (v) atomicAdd(&cnt_wt[i], v);
        }
    } else if (b < 80) {
        for (int e = (b - 16) * 256 + (int)threadIdx.x; e < E_WD; e += 64 * 256)
            atomicAdd(&cnt_wd[wd_dst[e]], 1);
    } else {
        for (int e = (b - 80) * 256 + (int)threadIdx.x; e < E_TD; e += 32 * 256)
            atomicAdd(&cnt_td[td_dst[e]], 1);
    }
}

// ---- 3 exclusive scans in one dispatch (block per relation), K=40 regs/thread ----
__global__ __launch_bounds__(256) void exscan3(
    const int* __restrict__ cnt_wt, int* __restrict__ row_wt, int* __restrict__ cur_wt,
    const int* __restrict__ cnt_wd, int* __restrict__ row_wd, int* __restrict__ cur_wd,
    const int* __restrict__ cnt_td, int* __restrict__ row_td, int* __restrict__ cur_td)
{
    const int* cnt; int* row; int* cur; int n;
    if (blockIdx.x == 0)      { cnt = cnt_wt; row = row_wt; cur = cur_wt; n = N_TOPIC; }
    else if (blockIdx.x == 1) { cnt = cnt_wd; row = row_wd; cur = cur_wd; n = N_DOC; }
    else                      { cnt = cnt_td; row = row_td; cur = cur_td; n = N_DOC; }

    __shared__ int wsum[4];
    const int t = threadIdx.x;
    const int lane = t & 63, wid = t >> 6;
    const int K = 40;
    int c[K];
    const int base = t * K;
    int tot = 0;
    #pragma unroll
    for (int k = 0; k < K; ++k) {
        int idx = base + k;
        c[k] = (idx < n) ? cnt[idx] : 0;
        tot += c[k];
    }
    int inc = tot;
    #pragma unroll
    for (int off = 1; off < 64; off <<= 1) {
        int u = __shfl_up(inc, off, 64);
        if (lane >= off) inc += u;
    }
    if (lane == 63) wsum[wid] = inc;
    __syncthreads();
    int woff = 0;
    for (int w = 0; w < wid; ++w) woff += wsum[w];
    int run = woff + inc - tot;
    #pragma unroll
    for (int k = 0; k < K; ++k) {
        int idx = base + k;
        if (idx < n) { row[idx] = run; cur[idx] = run; }
        run += c[k];
    }
}

// ---- fused scatter: blocks 0-15 wt (LDS-binned), 16-79 wd, 80-111 td ----
__global__ __launch_bounds__(256) void scatter_all(
    const int* __restrict__ wt_dst, const int* __restrict__ wd_dst, const int* __restrict__ td_dst,
    int* __restrict__ cur_wt, int* __restrict__ cur_wd, int* __restrict__ cur_td,
    int* __restrict__ csr_wt, int* __restrict__ csr_wd, int* __restrict__ csr_td)
{
    __shared__ int lc[N_TOPIC];
    __shared__ int lbase[N_TOPIC];
    int b = blockIdx.x;
    if (b < WT_BLOCKS) {
        for (int i = threadIdx.x; i < N_TOPIC; i += 256) lc[i] = 0;
        __syncthreads();
        const int per = E_WT / WT_BLOCKS;
        const int s = b * per;
        for (int i = s + (int)threadIdx.x; i < s + per; i += 256)
            atomicAdd(&lc[wt_dst[i]], 1);
        __syncthreads();
        for (int i = threadIdx.x; i < N_TOPIC; i += 256) {
            int v = lc[i];
            lbase[i] = v ? atomicAdd(&cur_wt[i], v) : 0;
            lc[i] = 0;
        }
        __syncthreads();
        for (int i = s + (int)threadIdx.x; i < s + per; i += 256) {
            int d = wt_dst[i];
            int pos = atomicAdd(&lc[d], 1);
            csr_wt[lbase[d] + pos] = i;
        }
    } else if (b < 80) {
        for (int e = (b - 16) * 256 + (int)threadIdx.x; e < E_WD; e += 64 * 256) {
            int pos = atomicAdd(&cur_wd[wd_dst[e]], 1);
            csr_wd[pos] = e;
        }
    } else {
        for (int e = (b - 80) * 256 + (int)threadIdx.x; e < E_TD; e += 32 * 256) {
            int pos = atomicAdd(&cur_td[td_dst[e]], 1);
            csr_td[pos] = e;
        }
    }
}

// ---- fused gather: waves 0..8191 topic chunks; 8192..28191 doc (node, rel) ----
__global__ __launch_bounds__(256) void gather_all(
    const __hip_bfloat16* __restrict__ fw, const __hip_bfloat16* __restrict__ ft,
    const float* __restrict__ w_wt, const int* __restrict__ wt_src,
    const int* __restrict__ csr_wt, const int* __restrict__ row_wt, const int* __restrict__ cnt_wt,
    const float* __restrict__ w_wd, const int* __restrict__ wd_src,
    const int* __restrict__ csr_wd, const int* __restrict__ row_wd, const int* __restrict__ cnt_wd,
    const float* __restrict__ w_td, const int* __restrict__ td_src,
    const int* __restrict__ csr_td, const int* __restrict__ row_td, const int* __restrict__ cnt_td,
    float* __restrict__ part, float* __restrict__ part_sumw,
    __hip_bfloat16* __restrict__ agg_wd, float* __restrict__ mw_wd,
    __hip_bfloat16* __restrict__ agg_td, float* __restrict__ mw_td)
{
    int gw = (blockIdx.x * 256 + (int)threadIdx.x) >> 6;
    int lane = threadIdx.x & 63;

    if (gw < N_TOPIC * TOPIC_C) {
        // ---- topic chunk path ----
        int node = gw >> 4;
        int chunk = gw & (TOPIC_C - 1);
        int start = row_wt[node], deg = cnt_wt[node];
        const unsigned short* T = (const unsigned short*)fw;
        float a0 = 0.f, a1 = 0.f, a2 = 0.f, a3 = 0.f, sw = 0.f;
        int j = chunk;
        for (; j + 3 * TOPIC_C < deg; j += 4 * TOPIC_C) {
            int e0 = csr_wt[start + j];
            int e1 = csr_wt[start + j + TOPIC_C];
            int e2 = csr_wt[start + j + 2 * TOPIC_C];
            int e3 = csr_wt[start + j + 3 * TOPIC_C];
            int s0 = wt_src[e0], s1 = wt_src[e1], s2 = wt_src[e2], s3 = wt_src[e3];
            float w0 = w_wt[e0], w1 = w_wt[e1], w2 = w_wt[e2], w3 = w_wt[e3];
            short4v v0 = *reinterpret_cast<const short4v*>(T + (size_t)s0 * DIM + lane * 4);
            short4v v1 = *reinterpret_cast<const short4v*>(T + (size_t)s1 * DIM + lane * 4);
            short4v v2 = *reinterpret_cast<const short4v*>(T + (size_t)s2 * DIM + lane * 4);
            short4v v3 = *reinterpret_cast<const short4v*>(T + (size_t)s3 * DIM + lane * 4);
            acc4(a0, a1, a2, a3, v0, w0);
            acc4(a0, a1, a2, a3, v1, w1);
            acc4(a0, a1, a2, a3, v2, w2);
            acc4(a0, a1, a2, a3, v3, w3);
            sw += w0 + w1 + w2 + w3;
        }
        for (; j < deg; j += TOPIC_C) {
            int e = csr_wt[start + j];
            int s = wt_src[e];
            float w = w_wt[e];
            short4v v = *reinterpret_cast<const short4v*>(T + (size_t)s * DIM + lane * 4);
            acc4(a0, a1, a2, a3, v, w);
            sw += w;
        }
        f32x4 r = {a0, a1, a2, a3};
        *reinterpret_cast<f32x4*>(part + ((size_t)chunk * N_TOPIC + node) * DIM + lane * 4) = r;
        if (lane == 0) part_sumw[chunk * N_TOPIC + node] = sw;
        return;
    }

    // ---- doc path ----
    int w2 = gw - N_TOPIC * TOPIC_C;
    if (w2 >= 2 * N_DOC) return;
    int rel = w2 >= N_DOC;
    int node = rel ? w2 - N_DOC : w2;

    const unsigned short* T = (const unsigned short*)(rel ? ft : fw);
    const float* ew = rel ? w_td : w_wd;
    const int* src  = rel ? td_src : wd_src;
    const int* csr  = rel ? csr_td : csr_wd;
    const int* rowp = rel ? row_td : row_wd;
    const int* cnt  = rel ? cnt_td : cnt_wd;
    __hip_bfloat16* agg = rel ? agg_td : agg_wd;
    float* mw = rel ? mw_td : mw_wd;

    int start = rowp[node], deg = cnt[node];
    float a0 = 0.f, a1 = 0.f, a2 = 0.f, a3 = 0.f, sw = 0.f;
    int j = 0;
    for (; j + 4 <= deg; j += 4) {
        int e0 = csr[start + j];
        int e1 = csr[start + j + 1];
        int e2 = csr[start + j + 2];
        int e3 = csr[start + j + 3];
        int s0 = src[e0], s1 = src[e1], s2 = src[e2], s3 = src[e3];
        float w0 = ew[e0], w1 = ew[e1], w2v = ew[e2], w3 = ew[e3];
        short4v v0 = *reinterpret_cast<const short4v*>(T + (size_t)s0 * DIM + lane * 4);
        short4v v1 = *reinterpret_cast<const short4v*>(T + (size_t)s1 * DIM + lane * 4);
        short4v v2 = *reinterpret_cast<const short4v*>(T + (size_t)s2 * DIM + lane * 4);
        short4v v3 = *reinterpret_cast<const short4v*>(T + (size_t)s3 * DIM + lane * 4);
        acc4(a0, a1, a2, a3, v0, w0);
        acc4(a0, a1, a2, a3, v1, w1);
        acc4(a0, a1, a2, a3, v2, w2v);
        acc4(a0, a1, a2, a3, v3, w3);
        sw += w0 + w1 + w2v + w3;
    }
    for (; j < deg; ++j) {
        int e = csr[start + j];
        int s = src[e];
        float w = ew[e];
        short4v v = *reinterpret_cast<const short4v*>(T + (size_t)s * DIM + lane * 4);
        acc4(a0, a1, a2, a3, v, w);
        sw += w;
    }
    float inv = 1.f / (float)(deg > 1 ? deg : 1);
    short4v r;
    r.x = f2bf(a0 * inv); r.y = f2bf(a1 * inv);
    r.z = f2bf(a2 * inv); r.w = f2bf(a3 * inv);
    *reinterpret_cast<short4v*>((unsigned short*)agg + (size_t)node * DIM + lane * 4) = r;
    if (lane == 0) mw[node] = sw * inv;
}
#define GATHER_WAVES (N_TOPIC * TOPIC_C + 2 * N_DOC)   // 28192 -> 7048 blocks exactly

// ---- reduce topic partials -> bf16 agg + f32 mw ----
__global__ __launch_bounds__(256) void topic_reduce(
    const float* __restrict__ part, const float* __restrict__ part_sumw,
    const int* __restrict__ cnt,
    __hip_bfloat16* __restrict__ agg, float* __restrict__ mw)
{
    int node = blockIdx.x;
    int dim = threadIdx.x;
    float s = 0.f;
    #pragma unroll
    for (int c = 0; c < TOPIC_C; ++c)
        s += part[((size_t)c * N_TOPIC + node) * DIM + dim];
    int d = cnt[node];
    float inv = 1.f / (float)(d > 1 ? d : 1);
    agg[(size_t)node * DIM + dim] = __float2bfloat16(s * inv);
    if (dim == 0) {
        float sw = 0.f;
        #pragma unroll
        for (int c = 0; c < TOPIC_C; ++c) sw += part_sumw[c * N_TOPIC + node];
        mw[node] = sw * inv;
    }
}

// ---- one wave per 16x16 output tile; waves 0..511 topic, 512..10511 doc ----
__device__ __forceinline__ f32x4 tile_mm(
    const unsigned short* __restrict__ A, const unsigned short* __restrict__ W,
    int rt, int ct, int lr, int kh, f32x4 acc)
{
    const unsigned short* Ab = A + (size_t)(rt * 16 + lr) * DIM + kh * 8;
    const unsigned short* Wb = W + (size_t)(ct * 16 + lr) * DIM + kh * 8;
    #pragma unroll
    for (int kk = 0; kk < 8; ++kk) {
        bf16x8 a = *reinterpret_cast<const bf16x8*>(Ab + kk * 32);
        bf16x8 b = *reinterpret_cast<const bf16x8*>(Wb + kk * 32);
        acc = __builtin_amdgcn_mfma_f32_16x16x32_bf16(a, b, acc, 0, 0, 0);
    }
    return acc;
}

__global__ __launch_bounds__(256) void gemm_all(
    const __hip_bfloat16* __restrict__ agg_wt, const __hip_bfloat16* __restrict__ wbt,
    const float* __restrict__ bt, const float* __restrict__ mw_t,
    const __hip_bfloat16* __restrict__ agg_wd, const __hip_bfloat16* __restrict__ wbd,
    const float* __restrict__ bd, const float* __restrict__ mw_d1,
    const __hip_bfloat16* __restrict__ agg_td, const __hip_bfloat16* __restrict__ wbtd,
    const float* __restrict__ btd, const float* __restrict__ mw_d2,
    float* __restrict__ out_topic, float* __restrict__ out_doc)
{
    int gw = blockIdx.x * 4 + (int)(threadIdx.x >> 6);
    int lane = threadIdx.x & 63;
    int lr = lane & 15, kh = lane >> 4;

    if (gw < (N_TOPIC / 16) * 16) {         // 512 topic tiles
        int rt = gw >> 4, ct = gw & 15;
        f32x4 acc = {0.f, 0.f, 0.f, 0.f};
        acc = tile_mm((const unsigned short*)agg_wt, (const unsigned short*)wbt, rt, ct, lr, kh, acc);
        float bb = bt[ct * 16 + lr];
        #pragma unroll
        for (int j = 0; j < 4; ++j) {
            int row = rt * 16 + kh * 4 + j;
            out_topic[(size_t)row * DIM + ct * 16 + lr] = acc[j] + bb * mw_t[row];
        }
    } else {
        int w2 = gw - (N_TOPIC / 16) * 16;  // 0..9999 doc tiles
        int rt = w2 >> 4, ct = w2 & 15;
        f32x4 acc = {0.f, 0.f, 0.f, 0.f};
        acc = tile_mm((const unsigned short*)agg_wd, (const unsigned short*)wbd, rt, ct, lr, kh, acc);
        acc = tile_mm((const unsigned short*)agg_td, (const unsigned short*)wbtd, rt, ct, lr, kh, acc);
        float bb1 = bd[ct * 16 + lr];
        float bb2 = btd[ct * 16 + lr];
        #pragma unroll
        for (int j = 0; j < 4; ++j) {
            int row = rt * 16 + kh * 4 + j;
            float v = acc[j] + bb1 * mw_d1[row] + bb2 * mw_d2[row];
            out_doc[(size_t)row * DIM + ct * 16 + lr] = fmaxf(v, 0.f);
        }
    }
}
#define GEMM_WAVES ((N_TOPIC / 16) * 16 + (N_DOC / 16) * 16)   // 10512 -> 2628 blocks exactly

extern "C" void kernel_launch(void* const* d_in, const int* in_sizes, int n_in,
                              void* d_out, int out_size, void* d_ws, size_t ws_size,
                              hipStream_t stream)
{
    const float* feat_word  = (const float*)d_in[0];
    const float* feat_topic = (const float*)d_in[1];
    /* feat_doc (d_in[2]) unused by the reference output */
    const int* wt_src = (const int*)d_in[3];
    const int* wt_dst = (const int*)d_in[4];
    const int* wd_src = (const int*)d_in[5];
    const int* wd_dst = (const int*)d_in[6];
    const int* td_src = (const int*)d_in[7];
    const int* td_dst = (const int*)d_in[8];
    const float* w_wt = (const float*)d_in[9];
    const float* w_wd = (const float*)d_in[10];
    const float* w_td = (const float*)d_in[11];
    const float* Wt   = (const float*)d_in[12];
    const float* bt   = (const float*)d_in[13];
    const float* Wd   = (const float*)d_in[14];
    const float* bd   = (const float*)d_in[15];
    const float* Wtd  = (const float*)d_in[16];
    const float* btd  = (const float*)d_in[17];

    char* ws = (char*)d_ws;
    // Workspace layout (bytes), ~37.9 MB total:
    __hip_bfloat16* fw     = (__hip_bfloat16*)(ws + 0);         // 15,360,000
    __hip_bfloat16* ft     = (__hip_bfloat16*)(ws + 15360000);  // 262,144
    __hip_bfloat16* wbt    = (__hip_bfloat16*)(ws + 15622144);  // 131,072
    __hip_bfloat16* wbd    = (__hip_bfloat16*)(ws + 15753216);  // 131,072
    __hip_bfloat16* wbtd   = (__hip_bfloat16*)(ws + 15884288);  // 131,072
    __hip_bfloat16* agg_wt = (__hip_bfloat16*)(ws + 16015360);  // 262,144 (bf16)
    __hip_bfloat16* agg_wd = (__hip_bfloat16*)(ws + 16277504);  // 5,120,000 (bf16)
    __hip_bfloat16* agg_td = (__hip_bfloat16*)(ws + 21397504);  // 5,120,000 (bf16)
    float* part      = (float*)(ws + 26517504);                 // 16*512*256*4 = 8,388,608
    float* part_sumw = (float*)(ws + 34906112);                 // 32,768
    float* mw_wt     = (float*)(ws + 34938880);                 // 2,048
    float* mw_wd     = (float*)(ws + 34940928);                 // 40,000
    float* mw_td     = (float*)(ws + 34980928);                 // 40,000
    int* cnt_wt = (int*)(ws + 35020928);                        // 2,048   } zero region
    int* cnt_wd = (int*)(ws + 35022976);                        // 40,000  }
    int* cnt_td = (int*)(ws + 35062976);                        // 40,000  } -> 35,102,976
    int* row_wt = (int*)(ws + 35102976);                        // 2,048
    int* row_wd = (int*)(ws + 35105024);                        // 40,000
    int* row_td = (int*)(ws + 35145024);                        // 40,000
    int* cur_wt = (int*)(ws + 35185024);                        // 2,048
    int* cur_wd = (int*)(ws + 35187072);                        // 40,000
    int* cur_td = (int*)(ws + 35227072);                        // 40,000
    int* csr_wt = (int*)(ws + 35267072);                        // 1,048,576
    int* csr_wd = (int*)(ws + 36315648);                        // 1,048,576
    int* csr_td = (int*)(ws + 37364224);                        // 524,288 -> 37,888,512

    float* out = (float*)d_out;
    float* out_topic = out + (size_t)N_WORD * DIM;
    float* out_doc   = out + (size_t)(N_WORD + N_TOPIC) * DIM;

    // zero histogram counters
    hipMemsetAsync(ws + 35020928, 0, 82048, stream);

    // fused casts + word passthrough
    cvt_all<<<CVT_TOTAL / 256, 256, 0, stream>>>(
        feat_word, feat_topic, Wt, Wd, Wtd, out, fw, ft, wbt, wbd, wbtd);

    // CSR build
    hist_all<<<112, 256, 0, stream>>>(wt_dst, wd_dst, td_dst, cnt_wt, cnt_wd, cnt_td);
    exscan3<<<3, 256, 0, stream>>>(cnt_wt, row_wt, cur_wt,
                                   cnt_wd, row_wd, cur_wd,
                                   cnt_td, row_td, cur_td);
    scatter_all<<<112, 256, 0, stream>>>(wt_dst, wd_dst, td_dst,
                                         cur_wt, cur_wd, cur_td,
                                         csr_wt, csr_wd, csr_td);

    // fused gathers (aggregate raw bf16 features, weighted mean)
    gather_all<<<GATHER_WAVES / 4, 256, 0, stream>>>(
        fw, ft,
        w_wt, wt_src, csr_wt, row_wt, cnt_wt,
        w_wd, wd_src, csr_wd, row_wd, cnt_wd,
        w_td, td_src, csr_td, row_td, cnt_td,
        part, part_sumw, agg_wd, mw_wd, agg_td, mw_td);
    topic_reduce<<<N_TOPIC, 256, 0, stream>>>(part, part_sumw, cnt_wt, agg_wt, mw_wt);

    // fused post-aggregation linears
    gemm_all<<<GEMM_WAVES / 4, 256, 0, stream>>>(
        agg_wt, wbt, bt, mw_wt,
        agg_wd, wbd, bd, mw_wd,
        agg_td, wbtd, btd, mw_td,
        out_topic, out_doc);
}